// Round 6
// baseline (265.904 us; speedup 1.0000x reference)
//
#include <hip/hip_runtime.h>
#include <math.h>

#define NB 512
#define NPQ 128
#define NY 1024
#define NO 256
#define NTOT 1408   // NPQ+NY+NO
#define SCALE_E 0.180336884f   // (1/sqrt(64)) * log2(e), folded upstream (R17)

typedef __attribute__((ext_vector_type(8))) short bf16x8;
typedef __attribute__((ext_vector_type(4))) float f32x4;

__device__ __forceinline__ unsigned short f2bf(float f) {
    unsigned int u = __float_as_uint(f);
    u += 0x7fffu + ((u >> 16) & 1u);   // RTNE
    return (unsigned short)(u >> 16);
}
__device__ __forceinline__ float bf2f(short s) {
    return __uint_as_float(((unsigned int)(unsigned short)s) << 16);
}

union U8  { bf16x8 v; unsigned long long u[2]; };
union U16 { bf16x8 v; uint4 u; };

// ============================================================================
// Kernel 0a: parallel weight folding, stage A. R17: b0g0 pre-scaled by E.
// ============================================================================
__global__ __launch_bounds__(256) void k_prepA(
    const float* __restrict__ emb,  const float* __restrict__ e0b2,
    const float* __restrict__ e0w2, const float* __restrict__ wq,
    const float* __restrict__ bq,   const float* __restrict__ wp,
    const float* __restrict__ bp,   const float* __restrict__ bk,
    const float* __restrict__ wvv,  const float* __restrict__ bv,
    const float* __restrict__ wo,   const float* __restrict__ bo,
    const float* __restrict__ e1b2, const float* __restrict__ e1w2,
    const float* __restrict__ e2b2, const float* __restrict__ e2w2,
    const float* __restrict__ nw1,  const float* __restrict__ nw2,
    float* __restrict__ W2qG, float* __restrict__ WvoG,
    float* __restrict__ scqG, float* __restrict__ b0g0,
    float* __restrict__ bvo,  float* __restrict__ BEP,
    unsigned short* __restrict__ W2P, unsigned short* __restrict__ WHP)
{
    const int tid = threadIdx.x, blk = blockIdx.x;

    if (blk < 16) {
        const int idx = blk*256 + tid;
        const int h = idx >> 6, j = idx & 63;
        float s0 = 0.f, s1 = 0.f, s2 = 0.f, s3 = 0.f;
        #pragma unroll 4
        for (int e = 0; e < 64; e += 4) {
            s0 = fmaf(e0w2[h*64+e],   wq[(e  )*64+j], s0);
            s1 = fmaf(e0w2[h*64+e+1], wq[(e+1)*64+j], s1);
            s2 = fmaf(e0w2[h*64+e+2], wq[(e+2)*64+j], s2);
            s3 = fmaf(e0w2[h*64+e+3], wq[(e+3)*64+j], s3);
        }
        W2qG[idx] = (s0 + s1) + (s2 + s3);
    } else if (blk < 32) {
        const int idx = (blk-16)*256 + tid;
        const int e = idx >> 6, o = idx & 63;
        float s0 = 0.f, s1 = 0.f, s2 = 0.f, s3 = 0.f;
        #pragma unroll 4
        for (int d = 0; d < 64; d += 4) {
            s0 = fmaf(wvv[e*64+d],   wo[(d  )*64+o], s0);
            s1 = fmaf(wvv[e*64+d+1], wo[(d+1)*64+o], s1);
            s2 = fmaf(wvv[e*64+d+2], wo[(d+2)*64+o], s2);
            s3 = fmaf(wvv[e*64+d+3], wo[(d+3)*64+o], s3);
        }
        WvoG[idx] = (s0 + s1) + (s2 + s3);
    } else if (blk < 38) {
        const int idx = (blk-32)*256 + tid;
        if (idx < 1536) {
            const int t = idx >> 9, rem = idx & 511;
            const int mt = rem >> 7, rem2 = rem & 127;
            const int kh = rem2 >> 6, lane = rem2 & 63;
            const int quad = lane >> 4, lq = lane & 15;
            const float* w2 = (t == 0) ? e0w2 : ((t == 1) ? e1w2 : e2w2);
            unsigned short v[8];
            #pragma unroll
            for (int j = 0; j < 8; ++j)
                v[j] = f2bf(w2[(kh*32 + quad*8 + j)*64 + mt*16 + lq]);
            *(uint4*)&W2P[(size_t)idx*8] = make_uint4(
                (unsigned int)v[0] | ((unsigned int)v[1] << 16),
                (unsigned int)v[2] | ((unsigned int)v[3] << 16),
                (unsigned int)v[4] | ((unsigned int)v[5] << 16),
                (unsigned int)v[6] | ((unsigned int)v[7] << 16));
        }
    } else if (blk < 42) {
        const int idx = 512 + (blk-38)*256 + tid;
        const int l = idx >> 9, rem = idx & 511;
        const int mt = rem >> 7, rem2 = rem & 127;
        const int kh = rem2 >> 6, lane = rem2 & 63;
        const int quad = lane >> 4, lq = lane & 15;
        const float* W = (l == 1) ? nw1 : nw2;
        unsigned short v[8];
        #pragma unroll
        for (int j = 0; j < 8; ++j)
            v[j] = f2bf(W[(kh*32 + quad*8 + j)*64 + mt*16 + lq]);
        *(uint4*)&WHP[(size_t)idx*8] = make_uint4(
            (unsigned int)v[0] | ((unsigned int)v[1] << 16),
            (unsigned int)v[2] | ((unsigned int)v[3] << 16),
            (unsigned int)v[4] | ((unsigned int)v[5] << 16),
            (unsigned int)v[6] | ((unsigned int)v[7] << 16));
    } else {
        __shared__ float scq[64];
        if (tid < 64) {
            const int j = tid;
            float s = bq[j];
            for (int e = 0; e < 64; ++e) s += (e0b2[e] + emb[e]) * wq[e*64+j];
            scq[j] = s;
            scqG[j] = s;
        }
        if (tid >= 64 && tid < 128) {
            const int o = tid - 64;
            float s = bo[o];
            for (int d = 0; d < 64; ++d) s += bv[d] * wo[d*64+o];
            bvo[o] = s;
        }
        {
            const int i = tid - 64;
            if (i >= 64 && i < 256) {
                const int idx = i - 64;   // 0..191
                const int t = idx >> 6, d = idx & 63;
                const float* b2 = (t == 0) ? e0b2 : ((t == 1) ? e1b2 : e2b2);
                BEP[idx] = b2[d] + emb[t*64 + d];
            }
        }
        __syncthreads();
        if (tid == 0) {
            float s0 = 0.f, s1 = 0.f, s2 = 0.f;
            for (int j = 0; j < 64; ++j) {
                s0 += scq[j] * wp[j];
                s1 += scq[j] * wp[64+j];
                s2 += scq[j] * (bp[j] + bk[j]);
            }
            b0g0[0] = SCALE_E * s0;    // R17: E folded upstream
            b0g0[1] = SCALE_E * s1;
            b0g0[2] = SCALE_E * s2;
        }
    }
}

// ============================================================================
// Kernel 0b: stage B. R17: AqkP / P3P / a0 pre-scaled by E.
// ============================================================================
__global__ __launch_bounds__(256) void k_prepB(
    const float* __restrict__ W2qG, const float* __restrict__ WvoG,
    const float* __restrict__ scqG,
    const float* __restrict__ wk, const float* __restrict__ wp,
    const float* __restrict__ bp, const float* __restrict__ bk,
    unsigned short* __restrict__ AqkP, unsigned short* __restrict__ P3P,
    float* __restrict__ a0, unsigned short* __restrict__ WHP)
{
    const int tid = threadIdx.x, blk = blockIdx.x;

    if (blk < 2) {
        const int idx = blk*256 + tid;
        const int fi = idx >> 6, lane = idx & 63;
        const int mt = fi >> 1, kh = fi & 1;
        const int quad = lane >> 4, lq = lane & 15;
        const int d = mt*16 + lq;
        unsigned short v[8];
        #pragma unroll
        for (int jj = 0; jj < 8; ++jj) {
            const int h = kh*32 + quad*8 + jj;
            float s0 = 0.f, s1 = 0.f, s2 = 0.f, s3 = 0.f;
            #pragma unroll 4
            for (int j = 0; j < 64; j += 4) {
                const float4 a = *(const float4*)&W2qG[h*64 + j];
                const float4 b = *(const float4*)&wk[d*64 + j];
                s0 = fmaf(a.x, b.x, s0); s1 = fmaf(a.y, b.y, s1);
                s2 = fmaf(a.z, b.z, s2); s3 = fmaf(a.w, b.w, s3);
            }
            v[jj] = f2bf(SCALE_E * ((s0 + s1) + (s2 + s3)));   // R17
        }
        *(uint4*)&AqkP[(size_t)idx*8] = make_uint4(
            (unsigned int)v[0] | ((unsigned int)v[1] << 16),
            (unsigned int)v[2] | ((unsigned int)v[3] << 16),
            (unsigned int)v[4] | ((unsigned int)v[5] << 16),
            (unsigned int)v[6] | ((unsigned int)v[7] << 16));
    } else if (blk == 2) {
        if (tid < 128) {
            const int idx = tid;
            const int kh = idx >> 6, lane = idx & 63;
            const int quad = lane >> 4, lq = lane & 15;
            unsigned short v[8];
            #pragma unroll
            for (int jj = 0; jj < 8; ++jj) {
                const int h = kh*32 + quad*8 + jj;
                float val = 0.f;
                if (lq == 0 || lq == 1) {
                    float s0 = 0.f, s1 = 0.f;
                    #pragma unroll 8
                    for (int j = 0; j < 64; j += 2) {
                        s0 = fmaf(W2qG[h*64+j],   wp[lq*64+j],   s0);
                        s1 = fmaf(W2qG[h*64+j+1], wp[lq*64+j+1], s1);
                    }
                    val = s0 + s1;
                } else if (lq == 2) {
                    float s0 = 0.f, s1 = 0.f;
                    #pragma unroll 8
                    for (int j = 0; j < 64; j += 2) {
                        s0 = fmaf(W2qG[h*64+j],   bp[j]   + bk[j],   s0);
                        s1 = fmaf(W2qG[h*64+j+1], bp[j+1] + bk[j+1], s1);
                    }
                    val = s0 + s1;
                }
                v[jj] = f2bf(SCALE_E * val);   // R17
            }
            *(uint4*)&P3P[(size_t)idx*8] = make_uint4(
                (unsigned int)v[0] | ((unsigned int)v[1] << 16),
                (unsigned int)v[2] | ((unsigned int)v[3] << 16),
                (unsigned int)v[4] | ((unsigned int)v[5] << 16),
                (unsigned int)v[6] | ((unsigned int)v[7] << 16));
        } else if (tid < 192) {
            const int d = tid - 128;
            float s0 = 0.f, s1 = 0.f, s2 = 0.f, s3 = 0.f;
            #pragma unroll 4
            for (int j = 0; j < 64; j += 4) {
                const float4 a = *(const float4*)&scqG[j];
                const float4 b = *(const float4*)&wk[d*64 + j];
                s0 = fmaf(a.x, b.x, s0); s1 = fmaf(a.y, b.y, s1);
                s2 = fmaf(a.z, b.z, s2); s3 = fmaf(a.w, b.w, s3);
            }
            a0[d] = SCALE_E * ((s0 + s1) + (s2 + s3));   // R17
        }
    } else {
        #pragma unroll
        for (int pass = 0; pass < 2; ++pass) {
            const int idx = pass*256 + tid;           // 0..511
            const int mt = idx >> 7, rem2 = idx & 127;
            const int kh = rem2 >> 6, lane = rem2 & 63;
            const int quad = lane >> 4, lq = lane & 15;
            unsigned short v[8];
            #pragma unroll
            for (int j = 0; j < 8; ++j)
                v[j] = f2bf(WvoG[(kh*32 + quad*8 + j)*64 + mt*16 + lq]);
            *(uint4*)&WHP[(size_t)idx*8] = make_uint4(
                (unsigned int)v[0] | ((unsigned int)v[1] << 16),
                (unsigned int)v[2] | ((unsigned int)v[3] << 16),
                (unsigned int)v[4] | ((unsigned int)v[5] << 16),
                (unsigned int)v[6] | ((unsigned int)v[7] << 16));
        }
    }
}

// ============================================================================
// Kernel 1: MERGED encoders + queries (byte-identical to R13/R14/R16 —
// verified; it consumes the pre-scaled AqkP/P3P/a0/b0g0 transparently, so
// QT/QP/QC come out E-scaled coherently).
// ============================================================================
__global__ __launch_bounds__(256) void k_encq(
    const float* __restrict__ pred, const float* __restrict__ prey,
    const float* __restrict__ obst,
    const unsigned short* __restrict__ W2P, const float* __restrict__ BEP,
    const float* __restrict__ e0w1, const float* __restrict__ e0b1,
    const float* __restrict__ e1w1, const float* __restrict__ e1b1,
    const float* __restrict__ e2w1, const float* __restrict__ e2b1,
    const unsigned short* __restrict__ AqkP, const float* __restrict__ a0,
    const unsigned short* __restrict__ P3P,  const float* __restrict__ b0g0,
    unsigned short* __restrict__ X, float* __restrict__ POS,
    float* __restrict__ QT, float* __restrict__ QP, float* __restrict__ QC)
{
    const int tid = threadIdx.x, lane = tid & 63, w = tid >> 6;
    const int lq = lane & 15, quad = lane >> 4;
    __shared__ __align__(16) short sH[4][32][68];

    if (blockIdx.x < 1408) {
        const int blk = blockIdx.x;
        int type, lrow0, cin, lsh, nmask, nbase;
        const float *st, *w1, *b1;
        if (blk < 128)       { type=0; lrow0=blk*512;         st=pred; w1=e0w1; b1=e0b1; cin=2; lsh=7;  nmask=NPQ-1; nbase=0; }
        else if (blk < 1152) { type=1; lrow0=(blk-128)*512;   st=prey; w1=e1w1; b1=e1b1; cin=2; lsh=10; nmask=NY-1;  nbase=NPQ; }
        else                 { type=2; lrow0=(blk-1152)*512;  st=obst; w1=e2w1; b1=e2b1; cin=3; lsh=8;  nmask=NO-1;  nbase=NPQ+NY; }

        bf16x8 wfrag[4][2];
        #pragma unroll
        for (int mt = 0; mt < 4; ++mt)
            #pragma unroll
            for (int kh = 0; kh < 2; ++kh)
                wfrag[mt][kh] = *(const bf16x8*)&W2P[(size_t)(((type*4 + mt)*2 + kh)*64 + lane)*8];

        float4 be[4];
        #pragma unroll
        for (int mt = 0; mt < 4; ++mt)
            be[mt] = *(const float4*)&BEP[type*64 + mt*16 + quad*4];

        float b1v[2][8], w0v[2][8], w1v[2][8], w2v[2][8];
        #pragma unroll
        for (int kh = 0; kh < 2; ++kh) {
            const int k0 = kh*32 + quad*8;
            *(float4*)&b1v[kh][0] = *(const float4*)&b1[k0];
            *(float4*)&b1v[kh][4] = *(const float4*)&b1[k0+4];
            *(float4*)&w0v[kh][0] = *(const float4*)&w1[k0];
            *(float4*)&w0v[kh][4] = *(const float4*)&w1[k0+4];
            *(float4*)&w1v[kh][0] = *(const float4*)&w1[64+k0];
            *(float4*)&w1v[kh][4] = *(const float4*)&w1[64+k0+4];
            if (cin == 3) {
                *(float4*)&w2v[kh][0] = *(const float4*)&w1[128+k0];
                *(float4*)&w2v[kh][4] = *(const float4*)&w1[128+k0+4];
            }
        }

        #pragma unroll
        for (int k = 0; k < 4; ++k) {
            const int i = tid*4 + k;
            const int r = i >> 1, c = i & 1;
            const int lr = lrow0 + r;
            const int pb = lr >> lsh, n = nbase + (lr & nmask);
            POS[((size_t)pb*NTOT + n)*2 + c] = st[(size_t)lr*cin + c];
        }

        for (int rt = 0; rt < 8; ++rt) {
            const int lr = lrow0 + w*128 + rt*16 + lq;
            float s0, s1, s2 = 0.f;
            if (cin == 2) {
                const float2 sv = *(const float2*)&st[(size_t)lr*2];
                s0 = sv.x; s1 = sv.y;
            } else {
                const float2 sv = *(const float2*)&st[(size_t)lr*3];
                s0 = sv.x; s1 = sv.y; s2 = st[(size_t)lr*3 + 2];
            }
            bf16x8 hb[2];
            #pragma unroll
            for (int kh = 0; kh < 2; ++kh)
                #pragma unroll
                for (int j = 0; j < 8; ++j) {
                    float a = b1v[kh][j] + s0*w0v[kh][j] + s1*w1v[kh][j];
                    if (cin == 3) a += s2*w2v[kh][j];
                    hb[kh][j] = (short)f2bf(fmaxf(a, 0.f));
                }

            f32x4 acc[4];
            #pragma unroll
            for (int mt = 0; mt < 4; ++mt) acc[mt] = (f32x4){0.f,0.f,0.f,0.f};
            #pragma unroll
            for (int mt = 0; mt < 4; ++mt) {
                acc[mt] = __builtin_amdgcn_mfma_f32_16x16x32_bf16(wfrag[mt][0], hb[0], acc[mt], 0, 0, 0);
                acc[mt] = __builtin_amdgcn_mfma_f32_16x16x32_bf16(wfrag[mt][1], hb[1], acc[mt], 0, 0, 0);
            }

            const int bb = lr >> lsh, n = nbase + (lr & nmask);
            unsigned short* xbase = X + ((size_t)bb*NTOT + n)*64;
            #pragma unroll
            for (int mt = 0; mt < 4; ++mt) {
                const unsigned int u0 = (unsigned int)f2bf(acc[mt][0] + be[mt].x)
                                      | ((unsigned int)f2bf(acc[mt][1] + be[mt].y) << 16);
                const unsigned int u1 = (unsigned int)f2bf(acc[mt][2] + be[mt].z)
                                      | ((unsigned int)f2bf(acc[mt][3] + be[mt].w) << 16);
                *(uint2*)(xbase + mt*16 + quad*4) = make_uint2(u0, u1);
            }
        }
    } else {
        const int b = blockIdx.x - 1408;
        const float w1r0 = e0w1[lane], w1r1 = e0w1[64+lane], b1r = e0b1[lane];
        {
            const float* sp = pred + ((size_t)b*NPQ + w*32)*2;
            #pragma unroll
            for (int r = 0; r < 32; ++r) {
                const float a = b1r + sp[2*r]*w1r0 + sp[2*r+1]*w1r1;
                sH[w][r][lane] = (short)f2bf(fmaxf(a, 0.f));
            }
        }

        bf16x8 wfrag[4][2], a3[2];
        #pragma unroll
        for (int mt = 0; mt < 4; ++mt)
            #pragma unroll
            for (int kh = 0; kh < 2; ++kh)
                wfrag[mt][kh] = *(const bf16x8*)&AqkP[(size_t)((mt*2 + kh)*64 + lane)*8];
        #pragma unroll
        for (int kh = 0; kh < 2; ++kh)
            a3[kh] = *(const bf16x8*)&P3P[(size_t)(kh*64 + lane)*8];

        float4 a0r[4];
        #pragma unroll
        for (int mt = 0; mt < 4; ++mt) a0r[mt] = *(const float4*)&a0[mt*16 + quad*4];
        const float c0 = b0g0[0], c1 = b0g0[1], c2 = b0g0[2];

        __syncthreads();

        for (int bt = 0; bt < 2; ++bt) {
            U8 hb0, hb1;
            const short* hp = &sH[w][bt*16 + lq][0];
            hb0.u[0] = *(const unsigned long long*)(hp + quad*8);
            hb0.u[1] = *(const unsigned long long*)(hp + quad*8 + 4);
            hb1.u[0] = *(const unsigned long long*)(hp + 32 + quad*8);
            hb1.u[1] = *(const unsigned long long*)(hp + 32 + quad*8 + 4);

            f32x4 acc[4], acc3;
            #pragma unroll
            for (int mt = 0; mt < 4; ++mt) acc[mt] = (f32x4){0.f,0.f,0.f,0.f};
            acc3 = (f32x4){0.f,0.f,0.f,0.f};
            #pragma unroll
            for (int mt = 0; mt < 4; ++mt) {
                acc[mt] = __builtin_amdgcn_mfma_f32_16x16x32_bf16(wfrag[mt][0], hb0.v, acc[mt], 0, 0, 0);
                acc[mt] = __builtin_amdgcn_mfma_f32_16x16x32_bf16(wfrag[mt][1], hb1.v, acc[mt], 0, 0, 0);
            }
            acc3 = __builtin_amdgcn_mfma_f32_16x16x32_bf16(a3[0], hb0.v, acc3, 0, 0, 0);
            acc3 = __builtin_amdgcn_mfma_f32_16x16x32_bf16(a3[1], hb1.v, acc3, 0, 0, 0);

            const int row = b*NPQ + w*32 + bt*16 + lq;
            #pragma unroll
            for (int mt = 0; mt < 4; ++mt) {
                *(float4*)&QT[(size_t)row*64 + mt*16 + quad*4] = make_float4(
                    acc[mt][0] + a0r[mt].x, acc[mt][1] + a0r[mt].y,
                    acc[mt][2] + a0r[mt].z, acc[mt][3] + a0r[mt].w);
            }
            if (quad == 0) {
                const float qp0 = acc3[0] + c0, qp1 = acc3[1] + c1, qs = acc3[2] + c2;
                const float p0 = pred[(size_t)row*2], p1 = pred[(size_t)row*2 + 1];
                QP[(size_t)row*2]     = qp0;
                QP[(size_t)row*2 + 1] = qp1;
                QC[row] = qp0*p0 + qp1*p1 + qs;
            }
        }
    }
}

// ============================================================================
// Kernel 3: flash attention + fused head.
// R23 = R20's S-block (swap REVERTED per R22 pre-commitment: swapped-S cost
// +7 µs — POS traffic 4x, qc-splat, VGPR 92->116) + NEW: S reads its X
// operands from LDS instead of global.
//  Staging is one iteration AHEAD in two layouts:
//   - sRowX[2][64][68]  row layout, written as 2xb128 straight from t0/t1
//     (data already in regs) -> S's bx fragments become ds_read_b128
//     (~120cy lgkm, issued before PV) replacing 8 per-wave-redundant global
//     loads (~200-400cy L2 vmcnt). Global X reads per block: 5x tile -> 1x.
//   - sXcT[3][64][68]  transposed for PV. THREE slots: staging tile kt+1
//     while PV reads tile kt-1 makes 2-slot ping-pong race (same slot).
//     PV@kt reads slot (kt-1)%3; staging@kt writes slot (kt+1)%3; tile kt
//     rests in slot kt%3. All distinct mod 3.
//  Everything else byte-level R20 (S math, sP layout, epilogue, head).
//  LDS 61,184 B -> still 2 blocks/CU (grid caps at 2 anyway).
//  Canaries: WRITE_SIZE ~256 KB, SQ_LDS_BANK_CONFLICT near 0 (sRowX
//  pattern is <=2-way), FETCH ~56.7e6 KB unchanged.
// ============================================================================
__global__ __launch_bounds__(256) void k_attn(
    const unsigned short* __restrict__ X, const float* __restrict__ POS,
    const float* __restrict__ QT, const float* __restrict__ QP,
    const float* __restrict__ QC,
    const unsigned short* __restrict__ WHP,
    const float* __restrict__ bvo, const float* __restrict__ nb1,
    const float* __restrict__ nb2,
    const float* __restrict__ nw3, const float* __restrict__ nb3,
    float* __restrict__ OUT)
{
    const int tid = threadIdx.x, b = blockIdx.x;
    const int w = tid >> 6, lane = tid & 63, lq = lane & 15, quad = lane >> 4;

    // LDS layout (R23):
    //   [0,      17408) sRowX[2][64][68]   | sA[128][68] (head ping, aliased)
    //   [17408,  43520) sXcT[3][64][68]    | sB[128][68] aliases first 17408 B
    //   [43520,  60928) sP[4][32][68]
    //   [60928,  61184) sw3[64]
    __shared__ __align__(16) char smem[61184];
    short (*sRowX)[64][68] = (short (*)[64][68])(smem);            // [2][64][68]
    short (*sXcT)[64][68]  = (short (*)[64][68])(smem + 17408);    // [3][64][68]
    short (*sP )[32][68]   = (short (*)[32][68])(smem + 43520);    // [4][32][68]
    short (*sA )[68]       = (short (*)[68])(smem);                // [128][68]
    short (*sB )[68]       = (short (*)[68])(smem + 17408);        // [128][68]
    float* sw3             = (float*)(smem + 60928);

    bf16x8 aq[2][2];
    #pragma unroll
    for (int qt = 0; qt < 2; ++qt) {
        const float* qrow = QT + ((size_t)b*NPQ + w*32 + qt*16 + lq)*64;
        #pragma unroll
        for (int kh = 0; kh < 2; ++kh)
            #pragma unroll
            for (int j = 0; j < 8; ++j)
                aq[qt][kh][j] = (short)f2bf(qrow[kh*32 + quad*8 + j]);
    }

    float qp0r[2][4], qp1r[2][4], lacc[2][4];
    f32x4 qcv[2];     // R17: C-initializer holding qcr per accumulator reg
    f32x4 O[2][4];
    #pragma unroll
    for (int qt = 0; qt < 2; ++qt)
        #pragma unroll
        for (int i = 0; i < 4; ++i) {
            const size_t g = (size_t)b*NPQ + w*32 + qt*16 + quad*4 + i;
            qcv[qt][i]  = QC[g];
            qp0r[qt][i] = -QP[2*g];
            qp1r[qt][i] = -QP[2*g+1];
            lacc[qt][i] = 0.f;
        }
    #pragma unroll
    for (int qt = 0; qt < 2; ++qt)
        #pragma unroll
        for (int nt = 0; nt < 4; ++nt) O[qt][nt] = (f32x4){0.f,0.f,0.f,0.f};

    const int skey = tid & 63, sd0 = (tid >> 6) * 16;

    // ---- prologue: stage tile 0 in both layouts ----
    {
        const unsigned short* gx = X + ((size_t)b*NTOT + skey)*64 + sd0;
        const uint4 p0 = *(const uint4*)(gx);
        const uint4 p1 = *(const uint4*)(gx + 8);
        *(uint4*)&sRowX[0][skey][sd0]     = p0;
        *(uint4*)&sRowX[0][skey][sd0 + 8] = p1;
        unsigned short tmp[16];
        *(uint4*)tmp = p0; *(uint4*)(tmp+8) = p1;
        #pragma unroll
        for (int j = 0; j < 16; ++j) sXcT[0][sd0+j][skey] = (short)tmp[j];
        __syncthreads();
    }

    for (int kt = 0; kt < 22; ++kt) {
        const int par  = kt & 1;          // sRowX slot holding tile kt
        const int pvS  = (kt + 2) % 3;    // sXcT slot holding tile kt-1
        const int stS  = (kt + 1) % 3;    // sXcT slot receiving tile kt+1

        // global loads for tile kt+1 (full iteration of latency slack)
        uint4 t0 = make_uint4(0,0,0,0), t1 = make_uint4(0,0,0,0);
        if (kt < 21) {
            const unsigned short* gx = X + ((size_t)b*NTOT + (kt+1)*64 + skey)*64 + sd0;
            t0 = *(const uint4*)(gx);
            t1 = *(const uint4*)(gx + 8);
        }

        // POS loads (global, L2-hot) + bx fragments from sRowX (LDS b128);
        // both issued before PV so PV hides their latency.
        float2 posv[4];
        U16 bxa[4], bxb[4];
        #pragma unroll
        for (int nt = 0; nt < 4; ++nt) {
            posv[nt] = *(const float2*)&POS[((size_t)b*NTOT + kt*64 + nt*16 + lq)*2];
            bxa[nt].u = *(const uint4*)&sRowX[par][nt*16 + lq][quad*8];
            bxb[nt].u = *(const uint4*)&sRowX[par][nt*16 + lq][32 + quad*8];
        }

        if (kt > 0) {
            #pragma unroll
            for (int kc = 0; kc < 2; ++kc) {
                U8 pa[2];
                #pragma unroll
                for (int qt = 0; qt < 2; ++qt) {
                    const short* pp = &sP[w][qt*16 + lq][kc*32 + quad*8];
                    pa[qt].u[0] = *(const unsigned long long*)pp;
                    pa[qt].u[1] = *(const unsigned long long*)(pp + 4);
                }
                #pragma unroll
                for (int nt = 0; nt < 4; ++nt) {
                    U8 bv;
                    const short* xp = &sXcT[pvS][nt*16 + lq][kc*32 + quad*8];
                    bv.u[0] = *(const unsigned long long*)xp;
                    bv.u[1] = *(const unsigned long long*)(xp + 4);
                    O[0][nt] = __builtin_amdgcn_mfma_f32_16x16x32_bf16(pa[0].v, bv.v, O[0][nt], 0, 0, 0);
                    O[1][nt] = __builtin_amdgcn_mfma_f32_16x16x32_bf16(pa[1].v, bv.v, O[1][nt], 0, 0, 0);
                }
            }
        }

        // Pins PV first (R20/R22 lesson: without it the scheduler lifts the
        // S work above PV and re-exposes operand latency).
        __builtin_amdgcn_sched_barrier(0);

        // S-block (R20 form): sa = mfma(aq, bx) -> D[q][key].
        #pragma unroll
        for (int nt = 0; nt < 4; ++nt) {
            const float pos0 = posv[nt].x;
            const float pos1 = posv[nt].y;
            #pragma unroll
            for (int qt = 0; qt < 2; ++qt) {
                f32x4 sa = qcv[qt];   // R17: qcr as C-init (row const matches reg i)
                sa = __builtin_amdgcn_mfma_f32_16x16x32_bf16(aq[qt][0], bxa[nt].v, sa, 0, 0, 0);
                sa = __builtin_amdgcn_mfma_f32_16x16x32_bf16(aq[qt][1], bxb[nt].v, sa, 0, 0, 0);
                #pragma unroll
                for (int i = 0; i < 4; ++i) {
                    float s = sa[i];
                    s = fmaf(qp0r[qt][i], pos0, s);
                    s = fmaf(qp1r[qt][i], pos1, s);
                    const float p = exp2f(s);   // R17: E pre-folded upstream
                    lacc[qt][i] += p;
                    sP[w][qt*16 + quad*4 + i][nt*16 + lq] = (short)f2bf(p);
                }
            }
        }

        // staging writes for tile kt+1 (both layouts)
        if (kt < 21) {
            *(uint4*)&sRowX[par^1][skey][sd0]     = t0;
            *(uint4*)&sRowX[par^1][skey][sd0 + 8] = t1;
            unsigned short tmp[16];
            *(uint4*)tmp = t0; *(uint4*)(tmp+8) = t1;
            #pragma unroll
            for (int j = 0; j < 16; ++j) sXcT[stS][sd0+j][skey] = (short)tmp[j];
        }

        __syncthreads();
    }

    // ---- final PV: tile 21 lives in sXcT slot 21%3 = 0 ----
    {
        #pragma unroll
        for (int kc = 0; kc < 2; ++kc) {
            U8 pa[2];
            #pragma unroll
            for (int qt = 0; qt < 2; ++qt) {
                const short* pp = &sP[w][qt*16 + lq][kc*32 + quad*8];
                pa[qt].u[0] = *(const unsigned long long*)pp;
                pa[qt].u[1] = *(const unsigned long long*)(pp + 4);
            }
            #pragma unroll
            for (int nt = 0; nt < 4; ++nt) {
                U8 bv;
                const short* xp = &sXcT[0][nt*16 + lq][kc*32 + quad*8];
                bv.u[0] = *(const unsigned long long*)xp;
                bv.u[1] = *(const unsigned long long*)(xp + 4);
                O[0][nt] = __builtin_amdgcn_mfma_f32_16x16x32_bf16(pa[0].v, bv.v, O[0][nt], 0, 0, 0);
                O[1][nt] = __builtin_amdgcn_mfma_f32_16x16x32_bf16(pa[1].v, bv.v, O[1][nt], 0, 0, 0);
            }
        }
    }

    // LDS-alias fence: all waves finish final-PV reads (sXcT[0] aliases sB
    // region) before the epilogue/head writes through the aliases.
    __syncthreads();

    // ---- attention epilogue -> sA (bf16) ----
    #pragma unroll
    for (int qt = 0; qt < 2; ++qt)
        #pragma unroll
        for (int i = 0; i < 4; ++i) {
            #pragma unroll
            for (int off = 1; off < 16; off <<= 1)
                lacc[qt][i] += __shfl_xor(lacc[qt][i], off);
            const float rl = 1.f / lacc[qt][i];
            const int row = w*32 + qt*16 + quad*4 + i;
            #pragma unroll
            for (int nt = 0; nt < 4; ++nt)
                sA[row][nt*16 + lq] = (short)f2bf(O[qt][nt][i] * rl);
        }
    if (tid < 64) sw3[tid] = nw3[tid];
    __syncthreads();   // sA complete before head reads (R2 lesson)

    // ---- fused head: 3 MFMA layers (verified k_head body) ----
    const float* Bs[3] = {bvo, nb1, nb2};
    for (int l = 0; l < 3; ++l) {
        bf16x8 wfrag[4][2];
        #pragma unroll
        for (int mt = 0; mt < 4; ++mt)
            #pragma unroll
            for (int kh = 0; kh < 2; ++kh)
                wfrag[mt][kh] = *(const bf16x8*)&WHP[(size_t)(((l*4 + mt)*2 + kh)*64 + lane)*8];
        const float* Bb = Bs[l];
        float be[4][4];
        #pragma unroll
        for (int mt = 0; mt < 4; ++mt)
            #pragma unroll
            for (int i = 0; i < 4; ++i) be[mt][i] = Bb[mt*16 + quad*4 + i];

        short (*src)[68] = (l & 1) ? sB : sA;
        short (*dst)[68] = (l & 1) ? sA : sB;
        const bool doRelu = (l >= 1);

        for (int bt = 0; bt < 2; ++bt) {
            U8 hb0, hb1;
            const short* hp = &src[w*32 + bt*16 + lq][0];
            hb0.u[0] = *(const unsigned long long*)(hp + quad*8);
            hb0.u[1] = *(const unsigned long long*)(hp + quad*8 + 4);
            hb1.u[0] = *(const unsigned long long*)(hp + 32 + quad*8);
            hb1.u[1] = *(const unsigned long long*)(hp + 32 + quad*8 + 4);

            f32x4 acc[4];
            #pragma unroll
            for (int mt = 0; mt < 4; ++mt) acc[mt] = (f32x4){0.f,0.f,0.f,0.f};
            #pragma unroll
            for (int mt = 0; mt < 4; ++mt) {
                acc[mt] = __builtin_amdgcn_mfma_f32_16x16x32_bf16(wfrag[mt][0], hb0.v, acc[mt], 0, 0, 0);
                acc[mt] = __builtin_amdgcn_mfma_f32_16x16x32_bf16(wfrag[mt][1], hb1.v, acc[mt], 0, 0, 0);
            }
            const int row = w*32 + bt*16 + lq;
            #pragma unroll
            for (int mt = 0; mt < 4; ++mt) {
                float v0 = acc[mt][0] + be[mt][0];
                float v1 = acc[mt][1] + be[mt][1];
                float v2 = acc[mt][2] + be[mt][2];
                float v3 = acc[mt][3] + be[mt][3];
                if (doRelu) {
                    v0 = fmaxf(v0, 0.f); v1 = fmaxf(v1, 0.f);
                    v2 = fmaxf(v2, 0.f); v3 = fmaxf(v3, 0.f);
                }
                const unsigned int u0 = (unsigned int)f2bf(v0) | ((unsigned int)f2bf(v1) << 16);
                const unsigned int u1 = (unsigned int)f2bf(v2) | ((unsigned int)f2bf(v3) << 16);
                *(uint2*)&dst[row][mt*16 + quad*4] = make_uint2(u0, u1);
            }
        }
        __syncthreads();
    }

    if (tid < 128) {
        const int row = tid;
        float acc = nb3[0];
        #pragma unroll 16
        for (int d = 0; d < 64; ++d) acc += bf2f(sB[row][d]) * sw3[d];
        OUT[(size_t)b*NPQ + row] = tanhf(acc);
    }
}

// ============================================================================
extern "C" void kernel_launch(void* const* d_in, const int* in_sizes, int n_in,
                              void* d_out, int out_size, void* d_ws, size_t ws_size,
                              hipStream_t stream)
{
    const float* pred = (const float*)d_in[0];
    const float* prey = (const float*)d_in[1];
    const float* obst = (const float*)d_in[2];
    const float* emb  = (const float*)d_in[4];
    const float* e0w1 = (const float*)d_in[5];
    const float* e0b1 = (const float*)d_in[6];
    const float* e0w2 = (const float*)d_in[7];
    const float* e0b2 = (const float*)d_in[8];
    const float* e1w1 = (const float*)d_in[9];
    const float* e1b1 = (const float*)d_in[10];
    const float* e1w2 = (const float*)d_in[11];
    const float* e1b2 = (const float*)d_in[12];
    const float* e2w1 = (const float*)d_in[13];
    const float* e2b1 = (const float*)d_in[14];
    const float* e2w2 = (const float*)d_in[15];
    const float* e2b2 = (const float*)d_in[16];
    const float* wq  = (const float*)d_in[17];
    const float* bq  = (const float*)d_in[18];
    const float* wk  = (const float*)d_in[19];
    const float* bk  = (const float*)d_in[20];
    const float* wvv = (const float*)d_in[21];
    const float* bv  = (const float*)d_in[22];
    const float* wp  = (const float*)d_in[23];
    const float* bp  = (const float*)d_in[24];
    const float* wo  = (const float*)d_in[25];
    const float* bo  = (const float*)d_in[26];
    const float* nw1 = (const float*)d_in[27];
    const float* nb1 = (const float*)d_in[28];
    const float* nw2 = (const float*)d_in[29];
    const float* nb2 = (const float*)d_in[30];
    const float* nw3 = (const float*)d_in[31];
    const float* nb3 = (const float*)d_in[32];

    char* ws = (char*)d_ws;
    unsigned short* X = (unsigned short*)ws;               // 92,274,688 B
    float* F    = (float*)(ws + 92274688);
    float* POS  = F;                  // 1,441,792
    float* QT   = POS + 1441792;      // 4,194,304
    float* QP   = QT  + 4194304;      // 131,072
    float* QC   = QP  + 131072;       // 65,536
    float* a0   = QC  + 65536;        // 64
    float* b0g0 = a0  + 64;           // 4
    float* bvo  = b0g0 + 4;           // 64
    float* BEP  = bvo + 64;           // 192
    float* W2qG = BEP + 192;          // 4,096
    float* WvoG = W2qG + 4096;        // 4,096
    float* scqG = WvoG + 4096;        // 64
    unsigned short* W2P  = (unsigned short*)(scqG + 64);   // 12,288
    unsigned short* AqkP = W2P + 12288;                    // 4,096
    unsigned short* P3P  = AqkP + 4096;                    // 1,024
    unsigned short* WHP  = P3P + 1024;                     // 12,288

    k_prepA<<<43, 256, 0, stream>>>(emb, e0b2, e0w2, wq, bq, wp, bp, bk,
        wvv, bv, wo, bo, e1b2, e1w2, e2b2, e2w2, nw1, nw2,
        W2qG, WvoG, scqG, b0g0, bvo, BEP, W2P, WHP);
    k_prepB<<<4, 256, 0, stream>>>(W2qG, WvoG, scqG, wk, wp, bp, bk,
        AqkP, P3P, a0, WHP);
    k_encq<<<1920, 256, 0, stream>>>(pred, prey, obst, W2P, BEP,
        e0w1, e0b1, e1w1, e1b1, e2w1, e2b1,
        AqkP, a0, P3P, b0g0, X, POS, QT, QP, QC);
    k_attn<<<512, 256, 0, stream>>>(X, POS, QT, QP, QC,
        WHP, bvo, nb1, nb2, nw3, nb3, (float*)d_out);
}

// Round 8
// 244.770 us; speedup vs baseline: 1.0863x; 1.0863x over previous
//
#include <hip/hip_runtime.h>
#include <math.h>

#define NB 512
#define NPQ 128
#define NY 1024
#define NO 256
#define NTOT 1408   // NPQ+NY+NO
#define SCALE_E 0.180336884f   // (1/sqrt(64)) * log2(e), folded upstream (R17)

typedef __attribute__((ext_vector_type(8))) short bf16x8;
typedef __attribute__((ext_vector_type(4))) float f32x4;

__device__ __forceinline__ unsigned short f2bf(float f) {
    unsigned int u = __float_as_uint(f);
    u += 0x7fffu + ((u >> 16) & 1u);   // RTNE
    return (unsigned short)(u >> 16);
}
__device__ __forceinline__ float bf2f(short s) {
    return __uint_as_float(((unsigned int)(unsigned short)s) << 16);
}

union U8  { bf16x8 v; unsigned long long u[2]; };
union U16 { bf16x8 v; uint4 u; };

// ============================================================================
// Kernel 0a: parallel weight folding, stage A. R17: b0g0 pre-scaled by E.
// ============================================================================
__global__ __launch_bounds__(256) void k_prepA(
    const float* __restrict__ emb,  const float* __restrict__ e0b2,
    const float* __restrict__ e0w2, const float* __restrict__ wq,
    const float* __restrict__ bq,   const float* __restrict__ wp,
    const float* __restrict__ bp,   const float* __restrict__ bk,
    const float* __restrict__ wvv,  const float* __restrict__ bv,
    const float* __restrict__ wo,   const float* __restrict__ bo,
    const float* __restrict__ e1b2, const float* __restrict__ e1w2,
    const float* __restrict__ e2b2, const float* __restrict__ e2w2,
    const float* __restrict__ nw1,  const float* __restrict__ nw2,
    float* __restrict__ W2qG, float* __restrict__ WvoG,
    float* __restrict__ scqG, float* __restrict__ b0g0,
    float* __restrict__ bvo,  float* __restrict__ BEP,
    unsigned short* __restrict__ W2P, unsigned short* __restrict__ WHP)
{
    const int tid = threadIdx.x, blk = blockIdx.x;

    if (blk < 16) {
        const int idx = blk*256 + tid;
        const int h = idx >> 6, j = idx & 63;
        float s0 = 0.f, s1 = 0.f, s2 = 0.f, s3 = 0.f;
        #pragma unroll 4
        for (int e = 0; e < 64; e += 4) {
            s0 = fmaf(e0w2[h*64+e],   wq[(e  )*64+j], s0);
            s1 = fmaf(e0w2[h*64+e+1], wq[(e+1)*64+j], s1);
            s2 = fmaf(e0w2[h*64+e+2], wq[(e+2)*64+j], s2);
            s3 = fmaf(e0w2[h*64+e+3], wq[(e+3)*64+j], s3);
        }
        W2qG[idx] = (s0 + s1) + (s2 + s3);
    } else if (blk < 32) {
        const int idx = (blk-16)*256 + tid;
        const int e = idx >> 6, o = idx & 63;
        float s0 = 0.f, s1 = 0.f, s2 = 0.f, s3 = 0.f;
        #pragma unroll 4
        for (int d = 0; d < 64; d += 4) {
            s0 = fmaf(wvv[e*64+d],   wo[(d  )*64+o], s0);
            s1 = fmaf(wvv[e*64+d+1], wo[(d+1)*64+o], s1);
            s2 = fmaf(wvv[e*64+d+2], wo[(d+2)*64+o], s2);
            s3 = fmaf(wvv[e*64+d+3], wo[(d+3)*64+o], s3);
        }
        WvoG[idx] = (s0 + s1) + (s2 + s3);
    } else if (blk < 38) {
        const int idx = (blk-32)*256 + tid;
        if (idx < 1536) {
            const int t = idx >> 9, rem = idx & 511;
            const int mt = rem >> 7, rem2 = rem & 127;
            const int kh = rem2 >> 6, lane = rem2 & 63;
            const int quad = lane >> 4, lq = lane & 15;
            const float* w2 = (t == 0) ? e0w2 : ((t == 1) ? e1w2 : e2w2);
            unsigned short v[8];
            #pragma unroll
            for (int j = 0; j < 8; ++j)
                v[j] = f2bf(w2[(kh*32 + quad*8 + j)*64 + mt*16 + lq]);
            *(uint4*)&W2P[(size_t)idx*8] = make_uint4(
                (unsigned int)v[0] | ((unsigned int)v[1] << 16),
                (unsigned int)v[2] | ((unsigned int)v[3] << 16),
                (unsigned int)v[4] | ((unsigned int)v[5] << 16),
                (unsigned int)v[6] | ((unsigned int)v[7] << 16));
        }
    } else if (blk < 42) {
        const int idx = 512 + (blk-38)*256 + tid;
        const int l = idx >> 9, rem = idx & 511;
        const int mt = rem >> 7, rem2 = rem & 127;
        const int kh = rem2 >> 6, lane = rem2 & 63;
        const int quad = lane >> 4, lq = lane & 15;
        const float* W = (l == 1) ? nw1 : nw2;
        unsigned short v[8];
        #pragma unroll
        for (int j = 0; j < 8; ++j)
            v[j] = f2bf(W[(kh*32 + quad*8 + j)*64 + mt*16 + lq]);
        *(uint4*)&WHP[(size_t)idx*8] = make_uint4(
            (unsigned int)v[0] | ((unsigned int)v[1] << 16),
            (unsigned int)v[2] | ((unsigned int)v[3] << 16),
            (unsigned int)v[4] | ((unsigned int)v[5] << 16),
            (unsigned int)v[6] | ((unsigned int)v[7] << 16));
    } else {
        __shared__ float scq[64];
        if (tid < 64) {
            const int j = tid;
            float s = bq[j];
            for (int e = 0; e < 64; ++e) s += (e0b2[e] + emb[e]) * wq[e*64+j];
            scq[j] = s;
            scqG[j] = s;
        }
        if (tid >= 64 && tid < 128) {
            const int o = tid - 64;
            float s = bo[o];
            for (int d = 0; d < 64; ++d) s += bv[d] * wo[d*64+o];
            bvo[o] = s;
        }
        {
            const int i = tid - 64;
            if (i >= 64 && i < 256) {
                const int idx = i - 64;   // 0..191
                const int t = idx >> 6, d = idx & 63;
                const float* b2 = (t == 0) ? e0b2 : ((t == 1) ? e1b2 : e2b2);
                BEP[idx] = b2[d] + emb[t*64 + d];
            }
        }
        __syncthreads();
        if (tid == 0) {
            float s0 = 0.f, s1 = 0.f, s2 = 0.f;
            for (int j = 0; j < 64; ++j) {
                s0 += scq[j] * wp[j];
                s1 += scq[j] * wp[64+j];
                s2 += scq[j] * (bp[j] + bk[j]);
            }
            b0g0[0] = SCALE_E * s0;    // R17: E folded upstream
            b0g0[1] = SCALE_E * s1;
            b0g0[2] = SCALE_E * s2;
        }
    }
}

// ============================================================================
// Kernel 0b: stage B. R17: AqkP / P3P / a0 pre-scaled by E.
// ============================================================================
__global__ __launch_bounds__(256) void k_prepB(
    const float* __restrict__ W2qG, const float* __restrict__ WvoG,
    const float* __restrict__ scqG,
    const float* __restrict__ wk, const float* __restrict__ wp,
    const float* __restrict__ bp, const float* __restrict__ bk,
    unsigned short* __restrict__ AqkP, unsigned short* __restrict__ P3P,
    float* __restrict__ a0, unsigned short* __restrict__ WHP)
{
    const int tid = threadIdx.x, blk = blockIdx.x;

    if (blk < 2) {
        const int idx = blk*256 + tid;
        const int fi = idx >> 6, lane = idx & 63;
        const int mt = fi >> 1, kh = fi & 1;
        const int quad = lane >> 4, lq = lane & 15;
        const int d = mt*16 + lq;
        unsigned short v[8];
        #pragma unroll
        for (int jj = 0; jj < 8; ++jj) {
            const int h = kh*32 + quad*8 + jj;
            float s0 = 0.f, s1 = 0.f, s2 = 0.f, s3 = 0.f;
            #pragma unroll 4
            for (int j = 0; j < 64; j += 4) {
                const float4 a = *(const float4*)&W2qG[h*64 + j];
                const float4 b = *(const float4*)&wk[d*64 + j];
                s0 = fmaf(a.x, b.x, s0); s1 = fmaf(a.y, b.y, s1);
                s2 = fmaf(a.z, b.z, s2); s3 = fmaf(a.w, b.w, s3);
            }
            v[jj] = f2bf(SCALE_E * ((s0 + s1) + (s2 + s3)));   // R17
        }
        *(uint4*)&AqkP[(size_t)idx*8] = make_uint4(
            (unsigned int)v[0] | ((unsigned int)v[1] << 16),
            (unsigned int)v[2] | ((unsigned int)v[3] << 16),
            (unsigned int)v[4] | ((unsigned int)v[5] << 16),
            (unsigned int)v[6] | ((unsigned int)v[7] << 16));
    } else if (blk == 2) {
        if (tid < 128) {
            const int idx = tid;
            const int kh = idx >> 6, lane = idx & 63;
            const int quad = lane >> 4, lq = lane & 15;
            unsigned short v[8];
            #pragma unroll
            for (int jj = 0; jj < 8; ++jj) {
                const int h = kh*32 + quad*8 + jj;
                float val = 0.f;
                if (lq == 0 || lq == 1) {
                    float s0 = 0.f, s1 = 0.f;
                    #pragma unroll 8
                    for (int j = 0; j < 64; j += 2) {
                        s0 = fmaf(W2qG[h*64+j],   wp[lq*64+j],   s0);
                        s1 = fmaf(W2qG[h*64+j+1], wp[lq*64+j+1], s1);
                    }
                    val = s0 + s1;
                } else if (lq == 2) {
                    float s0 = 0.f, s1 = 0.f;
                    #pragma unroll 8
                    for (int j = 0; j < 64; j += 2) {
                        s0 = fmaf(W2qG[h*64+j],   bp[j]   + bk[j],   s0);
                        s1 = fmaf(W2qG[h*64+j+1], bp[j+1] + bk[j+1], s1);
                    }
                    val = s0 + s1;
                }
                v[jj] = f2bf(SCALE_E * val);   // R17
            }
            *(uint4*)&P3P[(size_t)idx*8] = make_uint4(
                (unsigned int)v[0] | ((unsigned int)v[1] << 16),
                (unsigned int)v[2] | ((unsigned int)v[3] << 16),
                (unsigned int)v[4] | ((unsigned int)v[5] << 16),
                (unsigned int)v[6] | ((unsigned int)v[7] << 16));
        } else if (tid < 192) {
            const int d = tid - 128;
            float s0 = 0.f, s1 = 0.f, s2 = 0.f, s3 = 0.f;
            #pragma unroll 4
            for (int j = 0; j < 64; j += 4) {
                const float4 a = *(const float4*)&scqG[j];
                const float4 b = *(const float4*)&wk[d*64 + j];
                s0 = fmaf(a.x, b.x, s0); s1 = fmaf(a.y, b.y, s1);
                s2 = fmaf(a.z, b.z, s2); s3 = fmaf(a.w, b.w, s3);
            }
            a0[d] = SCALE_E * ((s0 + s1) + (s2 + s3));   // R17
        }
    } else {
        #pragma unroll
        for (int pass = 0; pass < 2; ++pass) {
            const int idx = pass*256 + tid;           // 0..511
            const int mt = idx >> 7, rem2 = idx & 127;
            const int kh = rem2 >> 6, lane = rem2 & 63;
            const int quad = lane >> 4, lq = lane & 15;
            unsigned short v[8];
            #pragma unroll
            for (int j = 0; j < 8; ++j)
                v[j] = f2bf(WvoG[(kh*32 + quad*8 + j)*64 + mt*16 + lq]);
            *(uint4*)&WHP[(size_t)idx*8] = make_uint4(
                (unsigned int)v[0] | ((unsigned int)v[1] << 16),
                (unsigned int)v[2] | ((unsigned int)v[3] << 16),
                (unsigned int)v[4] | ((unsigned int)v[5] << 16),
                (unsigned int)v[6] | ((unsigned int)v[7] << 16));
        }
    }
}

// ============================================================================
// Kernel 1: MERGED encoders + queries (restored to verified R13/R14/R16 body;
// the R24 submission accidentally dropped the hb0/hb1 loads in the query
// branch -> compile failure -> "container failed twice").
// ============================================================================
__global__ __launch_bounds__(256) void k_encq(
    const float* __restrict__ pred, const float* __restrict__ prey,
    const float* __restrict__ obst,
    const unsigned short* __restrict__ W2P, const float* __restrict__ BEP,
    const float* __restrict__ e0w1, const float* __restrict__ e0b1,
    const float* __restrict__ e1w1, const float* __restrict__ e1b1,
    const float* __restrict__ e2w1, const float* __restrict__ e2b1,
    const unsigned short* __restrict__ AqkP, const float* __restrict__ a0,
    const unsigned short* __restrict__ P3P,  const float* __restrict__ b0g0,
    unsigned short* __restrict__ X, float* __restrict__ POS,
    float* __restrict__ QT, float* __restrict__ QP, float* __restrict__ QC)
{
    const int tid = threadIdx.x, lane = tid & 63, w = tid >> 6;
    const int lq = lane & 15, quad = lane >> 4;
    __shared__ __align__(16) short sH[4][32][68];

    if (blockIdx.x < 1408) {
        const int blk = blockIdx.x;
        int type, lrow0, cin, lsh, nmask, nbase;
        const float *st, *w1, *b1;
        if (blk < 128)       { type=0; lrow0=blk*512;         st=pred; w1=e0w1; b1=e0b1; cin=2; lsh=7;  nmask=NPQ-1; nbase=0; }
        else if (blk < 1152) { type=1; lrow0=(blk-128)*512;   st=prey; w1=e1w1; b1=e1b1; cin=2; lsh=10; nmask=NY-1;  nbase=NPQ; }
        else                 { type=2; lrow0=(blk-1152)*512;  st=obst; w1=e2w1; b1=e2b1; cin=3; lsh=8;  nmask=NO-1;  nbase=NPQ+NY; }

        bf16x8 wfrag[4][2];
        #pragma unroll
        for (int mt = 0; mt < 4; ++mt)
            #pragma unroll
            for (int kh = 0; kh < 2; ++kh)
                wfrag[mt][kh] = *(const bf16x8*)&W2P[(size_t)(((type*4 + mt)*2 + kh)*64 + lane)*8];

        float4 be[4];
        #pragma unroll
        for (int mt = 0; mt < 4; ++mt)
            be[mt] = *(const float4*)&BEP[type*64 + mt*16 + quad*4];

        float b1v[2][8], w0v[2][8], w1v[2][8], w2v[2][8];
        #pragma unroll
        for (int kh = 0; kh < 2; ++kh) {
            const int k0 = kh*32 + quad*8;
            *(float4*)&b1v[kh][0] = *(const float4*)&b1[k0];
            *(float4*)&b1v[kh][4] = *(const float4*)&b1[k0+4];
            *(float4*)&w0v[kh][0] = *(const float4*)&w1[k0];
            *(float4*)&w0v[kh][4] = *(const float4*)&w1[k0+4];
            *(float4*)&w1v[kh][0] = *(const float4*)&w1[64+k0];
            *(float4*)&w1v[kh][4] = *(const float4*)&w1[64+k0+4];
            if (cin == 3) {
                *(float4*)&w2v[kh][0] = *(const float4*)&w1[128+k0];
                *(float4*)&w2v[kh][4] = *(const float4*)&w1[128+k0+4];
            }
        }

        #pragma unroll
        for (int k = 0; k < 4; ++k) {
            const int i = tid*4 + k;
            const int r = i >> 1, c = i & 1;
            const int lr = lrow0 + r;
            const int pb = lr >> lsh, n = nbase + (lr & nmask);
            POS[((size_t)pb*NTOT + n)*2 + c] = st[(size_t)lr*cin + c];
        }

        for (int rt = 0; rt < 8; ++rt) {
            const int lr = lrow0 + w*128 + rt*16 + lq;
            float s0, s1, s2 = 0.f;
            if (cin == 2) {
                const float2 sv = *(const float2*)&st[(size_t)lr*2];
                s0 = sv.x; s1 = sv.y;
            } else {
                const float2 sv = *(const float2*)&st[(size_t)lr*3];
                s0 = sv.x; s1 = sv.y; s2 = st[(size_t)lr*3 + 2];
            }
            bf16x8 hb[2];
            #pragma unroll
            for (int kh = 0; kh < 2; ++kh)
                #pragma unroll
                for (int j = 0; j < 8; ++j) {
                    float a = b1v[kh][j] + s0*w0v[kh][j] + s1*w1v[kh][j];
                    if (cin == 3) a += s2*w2v[kh][j];
                    hb[kh][j] = (short)f2bf(fmaxf(a, 0.f));
                }

            f32x4 acc[4];
            #pragma unroll
            for (int mt = 0; mt < 4; ++mt) acc[mt] = (f32x4){0.f,0.f,0.f,0.f};
            #pragma unroll
            for (int mt = 0; mt < 4; ++mt) {
                acc[mt] = __builtin_amdgcn_mfma_f32_16x16x32_bf16(wfrag[mt][0], hb[0], acc[mt], 0, 0, 0);
                acc[mt] = __builtin_amdgcn_mfma_f32_16x16x32_bf16(wfrag[mt][1], hb[1], acc[mt], 0, 0, 0);
            }

            const int bb = lr >> lsh, n = nbase + (lr & nmask);
            unsigned short* xbase = X + ((size_t)bb*NTOT + n)*64;
            #pragma unroll
            for (int mt = 0; mt < 4; ++mt) {
                const unsigned int u0 = (unsigned int)f2bf(acc[mt][0] + be[mt].x)
                                      | ((unsigned int)f2bf(acc[mt][1] + be[mt].y) << 16);
                const unsigned int u1 = (unsigned int)f2bf(acc[mt][2] + be[mt].z)
                                      | ((unsigned int)f2bf(acc[mt][3] + be[mt].w) << 16);
                *(uint2*)(xbase + mt*16 + quad*4) = make_uint2(u0, u1);
            }
        }
    } else {
        const int b = blockIdx.x - 1408;
        const float w1r0 = e0w1[lane], w1r1 = e0w1[64+lane], b1r = e0b1[lane];
        {
            const float* sp = pred + ((size_t)b*NPQ + w*32)*2;
            #pragma unroll
            for (int r = 0; r < 32; ++r) {
                const float a = b1r + sp[2*r]*w1r0 + sp[2*r+1]*w1r1;
                sH[w][r][lane] = (short)f2bf(fmaxf(a, 0.f));
            }
        }

        bf16x8 wfrag[4][2], a3[2];
        #pragma unroll
        for (int mt = 0; mt < 4; ++mt)
            #pragma unroll
            for (int kh = 0; kh < 2; ++kh)
                wfrag[mt][kh] = *(const bf16x8*)&AqkP[(size_t)((mt*2 + kh)*64 + lane)*8];
        #pragma unroll
        for (int kh = 0; kh < 2; ++kh)
            a3[kh] = *(const bf16x8*)&P3P[(size_t)(kh*64 + lane)*8];

        float4 a0r[4];
        #pragma unroll
        for (int mt = 0; mt < 4; ++mt) a0r[mt] = *(const float4*)&a0[mt*16 + quad*4];
        const float c0 = b0g0[0], c1 = b0g0[1], c2 = b0g0[2];

        __syncthreads();

        for (int bt = 0; bt < 2; ++bt) {
            U8 hb0, hb1;
            const short* hp = &sH[w][bt*16 + lq][0];
            hb0.u[0] = *(const unsigned long long*)(hp + quad*8);
            hb0.u[1] = *(const unsigned long long*)(hp + quad*8 + 4);
            hb1.u[0] = *(const unsigned long long*)(hp + 32 + quad*8);
            hb1.u[1] = *(const unsigned long long*)(hp + 32 + quad*8 + 4);

            f32x4 acc[4], acc3;
            #pragma unroll
            for (int mt = 0; mt < 4; ++mt) acc[mt] = (f32x4){0.f,0.f,0.f,0.f};
            acc3 = (f32x4){0.f,0.f,0.f,0.f};
            #pragma unroll
            for (int mt = 0; mt < 4; ++mt) {
                acc[mt] = __builtin_amdgcn_mfma_f32_16x16x32_bf16(wfrag[mt][0], hb0.v, acc[mt], 0, 0, 0);
                acc[mt] = __builtin_amdgcn_mfma_f32_16x16x32_bf16(wfrag[mt][1], hb1.v, acc[mt], 0, 0, 0);
            }
            acc3 = __builtin_amdgcn_mfma_f32_16x16x32_bf16(a3[0], hb0.v, acc3, 0, 0, 0);
            acc3 = __builtin_amdgcn_mfma_f32_16x16x32_bf16(a3[1], hb1.v, acc3, 0, 0, 0);

            const int row = b*NPQ + w*32 + bt*16 + lq;
            #pragma unroll
            for (int mt = 0; mt < 4; ++mt) {
                *(float4*)&QT[(size_t)row*64 + mt*16 + quad*4] = make_float4(
                    acc[mt][0] + a0r[mt].x, acc[mt][1] + a0r[mt].y,
                    acc[mt][2] + a0r[mt].z, acc[mt][3] + a0r[mt].w);
            }
            if (quad == 0) {
                const float qp0 = acc3[0] + c0, qp1 = acc3[1] + c1, qs = acc3[2] + c2;
                const float p0 = pred[(size_t)row*2], p1 = pred[(size_t)row*2 + 1];
                QP[(size_t)row*2]     = qp0;
                QP[(size_t)row*2 + 1] = qp1;
                QC[row] = qp0*p0 + qp1*p1 + qs;
            }
        }
    }
}

// ============================================================================
// Kernel 3: flash attention + fused head.
// R24 (resubmit) = R20 (best measured, 83 µs) + ONE change: bx/POS
// PREFETCHED ONE FULL ITERATION AHEAD.
//  R23 lesson: keep bx on the GLOBAL pipe (TA) — parallel to the DS pipe.
//  R20 residual: bx issued just above PV had only ~300-400 cyc of cover vs
//  ~600-900 cyc L3 latency. Now S(kt) consumes bx loaded during iteration
//  kt-1 -> slack = a full iteration.
//  Double-buffered registers; loop unrolled x2 so buffer choice is
//  compile-time (rule #20). sched_barrier(0) KEPT (R21/R22 lesson).
//  Canaries: WRITE_SIZE ~256 KB (no spill), bank conflicts 0.
// ============================================================================
__device__ __forceinline__ void attn_iter(
    int kt, int b, int w, int lq, int quad, int skey, int sd0,
    const unsigned short* __restrict__ X, const float* __restrict__ POS,
    const bf16x8 (&aq)[2][2], const f32x4 (&qcv)[2],
    const float (&qp0r)[2][4], const float (&qp1r)[2][4],
    float (&lacc)[2][4], f32x4 (&O)[2][4],
    short (*sP)[32][68], short (*sXc)[64][68],
    U16 (&curA)[4], U16 (&curB)[4], float2 (&curP)[4],
    U16 (&nxtA)[4], U16 (&nxtB)[4], float2 (&nxtP)[4])
{
    const int par = kt & 1;

    // staging loads for tile kt (consumed at end of this iteration)
    const unsigned short* gx = X + ((size_t)b*NTOT + kt*64 + skey)*64 + sd0;
    const uint4 t0 = *(const uint4*)(gx);
    const uint4 t1 = *(const uint4*)(gx + 8);

    // R24: prefetch bx/POS for tile kt+1 (consumed by S in NEXT iteration)
    if (kt < 21) {
        #pragma unroll
        for (int nt = 0; nt < 4; ++nt) {
            const unsigned short* xrow = X + ((size_t)b*NTOT + (kt+1)*64 + nt*16 + lq)*64;
            nxtA[nt].u = *(const uint4*)(xrow + quad*8);
            nxtB[nt].u = *(const uint4*)(xrow + 32 + quad*8);
            nxtP[nt]   = *(const float2*)&POS[((size_t)b*NTOT + (kt+1)*64 + nt*16 + lq)*2];
        }
    }

    if (kt > 0) {
        const int pb = par ^ 1;
        #pragma unroll
        for (int kc = 0; kc < 2; ++kc) {
            U8 pa[2];
            #pragma unroll
            for (int qt = 0; qt < 2; ++qt) {
                const short* pp = &sP[w][qt*16 + lq][kc*32 + quad*8];
                pa[qt].u[0] = *(const unsigned long long*)pp;
                pa[qt].u[1] = *(const unsigned long long*)(pp + 4);
            }
            #pragma unroll
            for (int nt = 0; nt < 4; ++nt) {
                U8 bv;
                const short* xp = &sXc[pb][nt*16 + lq][kc*32 + quad*8];
                bv.u[0] = *(const unsigned long long*)xp;
                bv.u[1] = *(const unsigned long long*)(xp + 4);
                O[0][nt] = __builtin_amdgcn_mfma_f32_16x16x32_bf16(pa[0].v, bv.v, O[0][nt], 0, 0, 0);
                O[1][nt] = __builtin_amdgcn_mfma_f32_16x16x32_bf16(pa[1].v, bv.v, O[1][nt], 0, 0, 0);
            }
        }
    }

    // Pins PV first (R20/R22 lesson) — S and its VALU tail stay below.
    __builtin_amdgcn_sched_barrier(0);

    // S-block (R20 form) consuming the CURRENT (prefetched last iter) bx/POS.
    #pragma unroll
    for (int nt = 0; nt < 4; ++nt) {
        const float pos0 = curP[nt].x;
        const float pos1 = curP[nt].y;
        #pragma unroll
        for (int qt = 0; qt < 2; ++qt) {
            f32x4 sa = qcv[qt];   // R17: qcr as C-init (row const matches reg i)
            sa = __builtin_amdgcn_mfma_f32_16x16x32_bf16(aq[qt][0], curA[nt].v, sa, 0, 0, 0);
            sa = __builtin_amdgcn_mfma_f32_16x16x32_bf16(aq[qt][1], curB[nt].v, sa, 0, 0, 0);
            #pragma unroll
            for (int i = 0; i < 4; ++i) {
                float s = sa[i];
                s = fmaf(qp0r[qt][i], pos0, s);
                s = fmaf(qp1r[qt][i], pos1, s);
                const float p = exp2f(s);   // R17: E pre-folded upstream
                lacc[qt][i] += p;
                sP[w][qt*16 + quad*4 + i][nt*16 + lq] = (short)f2bf(p);
            }
        }
    }

    // staging writes for tile kt (transposed)
    {
        unsigned short tmp[16];
        *(uint4*)tmp = t0; *(uint4*)(tmp+8) = t1;
        #pragma unroll
        for (int j = 0; j < 16; ++j) sXc[par][sd0+j][skey] = (short)tmp[j];
    }

    __syncthreads();
}

__global__ __launch_bounds__(256) void k_attn(
    const unsigned short* __restrict__ X, const float* __restrict__ POS,
    const float* __restrict__ QT, const float* __restrict__ QP,
    const float* __restrict__ QC,
    const unsigned short* __restrict__ WHP,
    const float* __restrict__ bvo, const float* __restrict__ nb1,
    const float* __restrict__ nb2,
    const float* __restrict__ nw3, const float* __restrict__ nb3,
    float* __restrict__ OUT)
{
    const int tid = threadIdx.x, b = blockIdx.x;
    const int w = tid >> 6, lane = tid & 63, lq = lane & 15, quad = lane >> 4;

    // LDS union: [0,17408) = sXc | sA ; [17408,34816) = sP | sB ; then sw3.
    __shared__ __align__(16) char smem[34816 + 256];
    short (*sXc)[64][68] = (short (*)[64][68])(smem);          // [2][64][68]
    short (*sP )[32][68] = (short (*)[32][68])(smem + 17408);  // [4][32][68]
    short (*sA )[68]     = (short (*)[68])(smem);              // [128][68]
    short (*sB )[68]     = (short (*)[68])(smem + 17408);      // [128][68]
    float* sw3           = (float*)(smem + 34816);

    bf16x8 aq[2][2];
    #pragma unroll
    for (int qt = 0; qt < 2; ++qt) {
        const float* qrow = QT + ((size_t)b*NPQ + w*32 + qt*16 + lq)*64;
        #pragma unroll
        for (int kh = 0; kh < 2; ++kh)
            #pragma unroll
            for (int j = 0; j < 8; ++j)
                aq[qt][kh][j] = (short)f2bf(qrow[kh*32 + quad*8 + j]);
    }

    float qp0r[2][4], qp1r[2][4], lacc[2][4];
    f32x4 qcv[2];     // R17: C-initializer holding qcr per accumulator reg
    f32x4 O[2][4];
    #pragma unroll
    for (int qt = 0; qt < 2; ++qt)
        #pragma unroll
        for (int i = 0; i < 4; ++i) {
            const size_t g = (size_t)b*NPQ + w*32 + qt*16 + quad*4 + i;
            qcv[qt][i]  = QC[g];
            qp0r[qt][i] = -QP[2*g];
            qp1r[qt][i] = -QP[2*g+1];
            lacc[qt][i] = 0.f;
        }
    #pragma unroll
    for (int qt = 0; qt < 2; ++qt)
        #pragma unroll
        for (int nt = 0; nt < 4; ++nt) O[qt][nt] = (f32x4){0.f,0.f,0.f,0.f};

    const int skey = tid & 63, sd0 = (tid >> 6) * 16;

    // R24 prologue: prefetch bx/POS for tile 0 into buffer A.
    U16 bxaA[4], bxbA[4], bxaB[4], bxbB[4];
    float2 posvA[4], posvB[4];
    #pragma unroll
    for (int nt = 0; nt < 4; ++nt) {
        const unsigned short* xrow = X + ((size_t)b*NTOT + nt*16 + lq)*64;
        bxaA[nt].u = *(const uint4*)(xrow + quad*8);
        bxbA[nt].u = *(const uint4*)(xrow + 32 + quad*8);
        posvA[nt]  = *(const float2*)&POS[((size_t)b*NTOT + nt*16 + lq)*2];
    }

    // main loop, unrolled x2 for compile-time cur/nxt buffer selection
    for (int ktb = 0; ktb < 22; ktb += 2) {
        attn_iter(ktb,   b, w, lq, quad, skey, sd0, X, POS, aq, qcv, qp0r, qp1r,
                  lacc, O, sP, sXc, bxaA, bxbA, posvA, bxaB, bxbB, posvB);
        attn_iter(ktb+1, b, w, lq, quad, skey, sd0, X, POS, aq, qcv, qp0r, qp1r,
                  lacc, O, sP, sXc, bxaB, bxbB, posvB, bxaA, bxbA, posvA);
    }

    // ---- final PV: tile 21 (par=1) ----
    {
        #pragma unroll
        for (int kc = 0; kc < 2; ++kc) {
            U8 pa[2];
            #pragma unroll
            for (int qt = 0; qt < 2; ++qt) {
                const short* pp = &sP[w][qt*16 + lq][kc*32 + quad*8];
                pa[qt].u[0] = *(const unsigned long long*)pp;
                pa[qt].u[1] = *(const unsigned long long*)(pp + 4);
            }
            #pragma unroll
            for (int nt = 0; nt < 4; ++nt) {
                U8 bv;
                const short* xp = &sXc[1][nt*16 + lq][kc*32 + quad*8];
                bv.u[0] = *(const unsigned long long*)xp;
                bv.u[1] = *(const unsigned long long*)(xp + 4);
                O[0][nt] = __builtin_amdgcn_mfma_f32_16x16x32_bf16(pa[0].v, bv.v, O[0][nt], 0, 0, 0);
                O[1][nt] = __builtin_amdgcn_mfma_f32_16x16x32_bf16(pa[1].v, bv.v, O[1][nt], 0, 0, 0);
            }
        }
    }

    // R18: LDS union hazard fence — all waves must finish reading sXc[1]/sP
    // before the epilogue overwrites them through the sA alias.
    __syncthreads();

    // ---- attention epilogue -> sA (bf16) ----
    #pragma unroll
    for (int qt = 0; qt < 2; ++qt)
        #pragma unroll
        for (int i = 0; i < 4; ++i) {
            #pragma unroll
            for (int off = 1; off < 16; off <<= 1)
                lacc[qt][i] += __shfl_xor(lacc[qt][i], off);
            const float rl = 1.f / lacc[qt][i];
            const int row = w*32 + qt*16 + quad*4 + i;
            #pragma unroll
            for (int nt = 0; nt < 4; ++nt)
                sA[row][nt*16 + lq] = (short)f2bf(O[qt][nt][i] * rl);
        }
    if (tid < 64) sw3[tid] = nw3[tid];
    __syncthreads();   // sA complete before head reads (R2 lesson)

    // ---- fused head: 3 MFMA layers (verified k_head body) ----
    const float* Bs[3] = {bvo, nb1, nb2};
    for (int l = 0; l < 3; ++l) {
        bf16x8 wfrag[4][2];
        #pragma unroll
        for (int mt = 0; mt < 4; ++mt)
            #pragma unroll
            for (int kh = 0; kh < 2; ++kh)
                wfrag[mt][kh] = *(const bf16x8*)&WHP[(size_t)(((l*4 + mt)*2 + kh)*64 + lane)*8];
        const float* Bb = Bs[l];
        float be[4][4];
        #pragma unroll
        for (int mt = 0; mt < 4; ++mt)
            #pragma unroll
            for (int i = 0; i < 4; ++i) be[mt][i] = Bb[mt*16 + quad*4 + i];

        short (*src)[68] = (l & 1) ? sB : sA;
        short (*dst)[68] = (l & 1) ? sA : sB;
        const bool doRelu = (l >= 1);

        for (int bt = 0; bt < 2; ++bt) {
            U8 hb0, hb1;
            const short* hp = &src[w*32 + bt*16 + lq][0];
            hb0.u[0] = *(const unsigned long long*)(hp + quad*8);
            hb0.u[1] = *(const unsigned long long*)(hp + quad*8 + 4);
            hb1.u[0] = *(const unsigned long long*)(hp + 32 + quad*8);
            hb1.u[1] = *(const unsigned long long*)(hp + 32 + quad*8 + 4);

            f32x4 acc[4];
            #pragma unroll
            for (int mt = 0; mt < 4; ++mt) acc[mt] = (f32x4){0.f,0.f,0.f,0.f};
            #pragma unroll
            for (int mt = 0; mt < 4; ++mt) {
                acc[mt] = __builtin_amdgcn_mfma_f32_16x16x32_bf16(wfrag[mt][0], hb0.v, acc[mt], 0, 0, 0);
                acc[mt] = __builtin_amdgcn_mfma_f32_16x16x32_bf16(wfrag[mt][1], hb1.v, acc[mt], 0, 0, 0);
            }
            const int row = w*32 + bt*16 + lq;
            #pragma unroll
            for (int mt = 0; mt < 4; ++mt) {
                float v0 = acc[mt][0] + be[mt][0];
                float v1 = acc[mt][1] + be[mt][1];
                float v2 = acc[mt][2] + be[mt][2];
                float v3 = acc[mt][3] + be[mt][3];
                if (doRelu) {
                    v0 = fmaxf(v0, 0.f); v1 = fmaxf(v1, 0.f);
                    v2 = fmaxf(v2, 0.f); v3 = fmaxf(v3, 0.f);
                }
                const unsigned int u0 = (unsigned int)f2bf(v0) | ((unsigned int)f2bf(v1) << 16);
                const unsigned int u1 = (unsigned int)f2bf(v2) | ((unsigned int)f2bf(v3) << 16);
                *(uint2*)&dst[row][mt*16 + quad*4] = make_uint2(u0, u1);
            }
        }
        __syncthreads();
    }

    if (tid < 128) {
        const int row = tid;
        float acc = nb3[0];
        #pragma unroll 16
        for (int d = 0; d < 64; ++d) acc += bf2f(sB[row][d]) * sw3[d];
        OUT[(size_t)b*NPQ + row] = tanhf(acc);
    }
}

// ============================================================================
extern "C" void kernel_launch(void* const* d_in, const int* in_sizes, int n_in,
                              void* d_out, int out_size, void* d_ws, size_t ws_size,
                              hipStream_t stream)
{
    const float* pred = (const float*)d_in[0];
    const float* prey = (const float*)d_in[1];
    const float* obst = (const float*)d_in[2];
    const float* emb  = (const float*)d_in[4];
    const float* e0w1 = (const float*)d_in[5];
    const float* e0b1 = (const float*)d_in[6];
    const float* e0w2 = (const float*)d_in[7];
    const float* e0b2 = (const float*)d_in[8];
    const float* e1w1 = (const float*)d_in[9];
    const float* e1b1 = (const float*)d_in[10];
    const float* e1w2 = (const float*)d_in[11];
    const float* e1b2 = (const float*)d_in[12];
    const float* e2w1 = (const float*)d_in[13];
    const float* e2b1 = (const float*)d_in[14];
    const float* e2w2 = (const float*)d_in[15];
    const float* e2b2 = (const float*)d_in[16];
    const float* wq  = (const float*)d_in[17];
    const float* bq  = (const float*)d_in[18];
    const float* wk  = (const float*)d_in[19];
    const float* bk  = (const float*)d_in[20];
    const float* wvv = (const float*)d_in[21];
    const float* bv  = (const float*)d_in[22];
    const float* wp  = (const float*)d_in[23];
    const float* bp  = (const float*)d_in[24];
    const float* wo  = (const float*)d_in[25];
    const float* bo  = (const float*)d_in[26];
    const float* nw1 = (const float*)d_in[27];
    const float* nb1 = (const float*)d_in[28];
    const float* nw2 = (const float*)d_in[29];
    const float* nb2 = (const float*)d_in[30];
    const float* nw3 = (const float*)d_in[31];
    const float* nb3 = (const float*)d_in[32];

    char* ws = (char*)d_ws;
    unsigned short* X = (unsigned short*)ws;               // 92,274,688 B
    float* F    = (float*)(ws + 92274688);
    float* POS  = F;                  // 1,441,792
    float* QT   = POS + 1441792;      // 4,194,304
    float* QP   = QT  + 4194304;      // 131,072
    float* QC   = QP  + 131072;       // 65,536
    float* a0   = QC  + 65536;        // 64
    float* b0g0 = a0  + 64;           // 4
    float* bvo  = b0g0 + 4;           // 64
    float* BEP  = bvo + 64;           // 192
    float* W2qG = BEP + 192;          // 4,096
    float* WvoG = W2qG + 4096;        // 4,096
    float* scqG = WvoG + 4096;        // 64
    unsigned short* W2P  = (unsigned short*)(scqG + 64);   // 12,288
    unsigned short* AqkP = W2P + 12288;                    // 4,096
    unsigned short* P3P  = AqkP + 4096;                    // 1,024
    unsigned short* WHP  = P3P + 1024;                     // 12,288

    k_prepA<<<43, 256, 0, stream>>>(emb, e0b2, e0w2, wq, bq, wp, bp, bk,
        wvv, bv, wo, bo, e1b2, e1w2, e2b2, e2w2, nw1, nw2,
        W2qG, WvoG, scqG, b0g0, bvo, BEP, W2P, WHP);
    k_prepB<<<4, 256, 0, stream>>>(W2qG, WvoG, scqG, wk, wp, bp, bk,
        AqkP, P3P, a0, WHP);
    k_encq<<<1920, 256, 0, stream>>>(pred, prey, obst, W2P, BEP,
        e0w1, e0b1, e1w1, e1b1, e2w1, e2b1,
        AqkP, a0, P3P, b0g0, X, POS, QT, QP, QC);
    k_attn<<<512, 256, 0, stream>>>(X, POS, QT, QP, QC,
        WHP, bvo, nb1, nb2, nw3, nb3, (float*)d_out);
}

// Round 9
// 244.500 us; speedup vs baseline: 1.0875x; 1.0011x over previous
//
#include <hip/hip_runtime.h>
#include <math.h>

#define NB 512
#define NPQ 128
#define NY 1024
#define NO 256
#define NTOT 1408   // NPQ+NY+NO
#define SCALE_E 0.180336884f   // (1/sqrt(64)) * log2(e), folded upstream (R17)

typedef __attribute__((ext_vector_type(8))) short bf16x8;
typedef __attribute__((ext_vector_type(4))) float f32x4;

__device__ __forceinline__ unsigned short f2bf(float f) {
    unsigned int u = __float_as_uint(f);
    u += 0x7fffu + ((u >> 16) & 1u);   // RTNE
    return (unsigned short)(u >> 16);
}
__device__ __forceinline__ float bf2f(short s) {
    return __uint_as_float(((unsigned int)(unsigned short)s) << 16);
}

union U8  { bf16x8 v; unsigned long long u[2]; };
union U16 { bf16x8 v; uint4 u; };

// ============================================================================
// Kernel 0a: parallel weight folding, stage A. R17: b0g0 pre-scaled by E.
// ============================================================================
__global__ __launch_bounds__(256) void k_prepA(
    const float* __restrict__ emb,  const float* __restrict__ e0b2,
    const float* __restrict__ e0w2, const float* __restrict__ wq,
    const float* __restrict__ bq,   const float* __restrict__ wp,
    const float* __restrict__ bp,   const float* __restrict__ bk,
    const float* __restrict__ wvv,  const float* __restrict__ bv,
    const float* __restrict__ wo,   const float* __restrict__ bo,
    const float* __restrict__ e1b2, const float* __restrict__ e1w2,
    const float* __restrict__ e2b2, const float* __restrict__ e2w2,
    const float* __restrict__ nw1,  const float* __restrict__ nw2,
    float* __restrict__ W2qG, float* __restrict__ WvoG,
    float* __restrict__ scqG, float* __restrict__ b0g0,
    float* __restrict__ bvo,  float* __restrict__ BEP,
    unsigned short* __restrict__ W2P, unsigned short* __restrict__ WHP)
{
    const int tid = threadIdx.x, blk = blockIdx.x;

    if (blk < 16) {
        const int idx = blk*256 + tid;
        const int h = idx >> 6, j = idx & 63;
        float s0 = 0.f, s1 = 0.f, s2 = 0.f, s3 = 0.f;
        #pragma unroll 4
        for (int e = 0; e < 64; e += 4) {
            s0 = fmaf(e0w2[h*64+e],   wq[(e  )*64+j], s0);
            s1 = fmaf(e0w2[h*64+e+1], wq[(e+1)*64+j], s1);
            s2 = fmaf(e0w2[h*64+e+2], wq[(e+2)*64+j], s2);
            s3 = fmaf(e0w2[h*64+e+3], wq[(e+3)*64+j], s3);
        }
        W2qG[idx] = (s0 + s1) + (s2 + s3);
    } else if (blk < 32) {
        const int idx = (blk-16)*256 + tid;
        const int e = idx >> 6, o = idx & 63;
        float s0 = 0.f, s1 = 0.f, s2 = 0.f, s3 = 0.f;
        #pragma unroll 4
        for (int d = 0; d < 64; d += 4) {
            s0 = fmaf(wvv[e*64+d],   wo[(d  )*64+o], s0);
            s1 = fmaf(wvv[e*64+d+1], wo[(d+1)*64+o], s1);
            s2 = fmaf(wvv[e*64+d+2], wo[(d+2)*64+o], s2);
            s3 = fmaf(wvv[e*64+d+3], wo[(d+3)*64+o], s3);
        }
        WvoG[idx] = (s0 + s1) + (s2 + s3);
    } else if (blk < 38) {
        const int idx = (blk-32)*256 + tid;
        if (idx < 1536) {
            const int t = idx >> 9, rem = idx & 511;
            const int mt = rem >> 7, rem2 = rem & 127;
            const int kh = rem2 >> 6, lane = rem2 & 63;
            const int quad = lane >> 4, lq = lane & 15;
            const float* w2 = (t == 0) ? e0w2 : ((t == 1) ? e1w2 : e2w2);
            unsigned short v[8];
            #pragma unroll
            for (int j = 0; j < 8; ++j)
                v[j] = f2bf(w2[(kh*32 + quad*8 + j)*64 + mt*16 + lq]);
            *(uint4*)&W2P[(size_t)idx*8] = make_uint4(
                (unsigned int)v[0] | ((unsigned int)v[1] << 16),
                (unsigned int)v[2] | ((unsigned int)v[3] << 16),
                (unsigned int)v[4] | ((unsigned int)v[5] << 16),
                (unsigned int)v[6] | ((unsigned int)v[7] << 16));
        }
    } else if (blk < 42) {
        const int idx = 512 + (blk-38)*256 + tid;
        const int l = idx >> 9, rem = idx & 511;
        const int mt = rem >> 7, rem2 = rem & 127;
        const int kh = rem2 >> 6, lane = rem2 & 63;
        const int quad = lane >> 4, lq = lane & 15;
        const float* W = (l == 1) ? nw1 : nw2;
        unsigned short v[8];
        #pragma unroll
        for (int j = 0; j < 8; ++j)
            v[j] = f2bf(W[(kh*32 + quad*8 + j)*64 + mt*16 + lq]);
        *(uint4*)&WHP[(size_t)idx*8] = make_uint4(
            (unsigned int)v[0] | ((unsigned int)v[1] << 16),
            (unsigned int)v[2] | ((unsigned int)v[3] << 16),
            (unsigned int)v[4] | ((unsigned int)v[5] << 16),
            (unsigned int)v[6] | ((unsigned int)v[7] << 16));
    } else {
        __shared__ float scq[64];
        if (tid < 64) {
            const int j = tid;
            float s = bq[j];
            for (int e = 0; e < 64; ++e) s += (e0b2[e] + emb[e]) * wq[e*64+j];
            scq[j] = s;
            scqG[j] = s;
        }
        if (tid >= 64 && tid < 128) {
            const int o = tid - 64;
            float s = bo[o];
            for (int d = 0; d < 64; ++d) s += bv[d] * wo[d*64+o];
            bvo[o] = s;
        }
        {
            const int i = tid - 64;
            if (i >= 64 && i < 256) {
                const int idx = i - 64;   // 0..191
                const int t = idx >> 6, d = idx & 63;
                const float* b2 = (t == 0) ? e0b2 : ((t == 1) ? e1b2 : e2b2);
                BEP[idx] = b2[d] + emb[t*64 + d];
            }
        }
        __syncthreads();
        if (tid == 0) {
            float s0 = 0.f, s1 = 0.f, s2 = 0.f;
            for (int j = 0; j < 64; ++j) {
                s0 += scq[j] * wp[j];
                s1 += scq[j] * wp[64+j];
                s2 += scq[j] * (bp[j] + bk[j]);
            }
            b0g0[0] = SCALE_E * s0;    // R17: E folded upstream
            b0g0[1] = SCALE_E * s1;
            b0g0[2] = SCALE_E * s2;
        }
    }
}

// ============================================================================
// Kernel 0b: stage B. R17: AqkP / P3P / a0 pre-scaled by E.
// ============================================================================
__global__ __launch_bounds__(256) void k_prepB(
    const float* __restrict__ W2qG, const float* __restrict__ WvoG,
    const float* __restrict__ scqG,
    const float* __restrict__ wk, const float* __restrict__ wp,
    const float* __restrict__ bp, const float* __restrict__ bk,
    unsigned short* __restrict__ AqkP, unsigned short* __restrict__ P3P,
    float* __restrict__ a0, unsigned short* __restrict__ WHP)
{
    const int tid = threadIdx.x, blk = blockIdx.x;

    if (blk < 2) {
        const int idx = blk*256 + tid;
        const int fi = idx >> 6, lane = idx & 63;
        const int mt = fi >> 1, kh = fi & 1;
        const int quad = lane >> 4, lq = lane & 15;
        const int d = mt*16 + lq;
        unsigned short v[8];
        #pragma unroll
        for (int jj = 0; jj < 8; ++jj) {
            const int h = kh*32 + quad*8 + jj;
            float s0 = 0.f, s1 = 0.f, s2 = 0.f, s3 = 0.f;
            #pragma unroll 4
            for (int j = 0; j < 64; j += 4) {
                const float4 a = *(const float4*)&W2qG[h*64 + j];
                const float4 b = *(const float4*)&wk[d*64 + j];
                s0 = fmaf(a.x, b.x, s0); s1 = fmaf(a.y, b.y, s1);
                s2 = fmaf(a.z, b.z, s2); s3 = fmaf(a.w, b.w, s3);
            }
            v[jj] = f2bf(SCALE_E * ((s0 + s1) + (s2 + s3)));   // R17
        }
        *(uint4*)&AqkP[(size_t)idx*8] = make_uint4(
            (unsigned int)v[0] | ((unsigned int)v[1] << 16),
            (unsigned int)v[2] | ((unsigned int)v[3] << 16),
            (unsigned int)v[4] | ((unsigned int)v[5] << 16),
            (unsigned int)v[6] | ((unsigned int)v[7] << 16));
    } else if (blk == 2) {
        if (tid < 128) {
            const int idx = tid;
            const int kh = idx >> 6, lane = idx & 63;
            const int quad = lane >> 4, lq = lane & 15;
            unsigned short v[8];
            #pragma unroll
            for (int jj = 0; jj < 8; ++jj) {
                const int h = kh*32 + quad*8 + jj;
                float val = 0.f;
                if (lq == 0 || lq == 1) {
                    float s0 = 0.f, s1 = 0.f;
                    #pragma unroll 8
                    for (int j = 0; j < 64; j += 2) {
                        s0 = fmaf(W2qG[h*64+j],   wp[lq*64+j],   s0);
                        s1 = fmaf(W2qG[h*64+j+1], wp[lq*64+j+1], s1);
                    }
                    val = s0 + s1;
                } else if (lq == 2) {
                    float s0 = 0.f, s1 = 0.f;
                    #pragma unroll 8
                    for (int j = 0; j < 64; j += 2) {
                        s0 = fmaf(W2qG[h*64+j],   bp[j]   + bk[j],   s0);
                        s1 = fmaf(W2qG[h*64+j+1], bp[j+1] + bk[j+1], s1);
                    }
                    val = s0 + s1;
                }
                v[jj] = f2bf(SCALE_E * val);   // R17
            }
            *(uint4*)&P3P[(size_t)idx*8] = make_uint4(
                (unsigned int)v[0] | ((unsigned int)v[1] << 16),
                (unsigned int)v[2] | ((unsigned int)v[3] << 16),
                (unsigned int)v[4] | ((unsigned int)v[5] << 16),
                (unsigned int)v[6] | ((unsigned int)v[7] << 16));
        } else if (tid < 192) {
            const int d = tid - 128;
            float s0 = 0.f, s1 = 0.f, s2 = 0.f, s3 = 0.f;
            #pragma unroll 4
            for (int j = 0; j < 64; j += 4) {
                const float4 a = *(const float4*)&scqG[j];
                const float4 b = *(const float4*)&wk[d*64 + j];
                s0 = fmaf(a.x, b.x, s0); s1 = fmaf(a.y, b.y, s1);
                s2 = fmaf(a.z, b.z, s2); s3 = fmaf(a.w, b.w, s3);
            }
            a0[d] = SCALE_E * ((s0 + s1) + (s2 + s3));   // R17
        }
    } else {
        #pragma unroll
        for (int pass = 0; pass < 2; ++pass) {
            const int idx = pass*256 + tid;           // 0..511
            const int mt = idx >> 7, rem2 = idx & 127;
            const int kh = rem2 >> 6, lane = rem2 & 63;
            const int quad = lane >> 4, lq = lane & 15;
            unsigned short v[8];
            #pragma unroll
            for (int j = 0; j < 8; ++j)
                v[j] = f2bf(WvoG[(kh*32 + quad*8 + j)*64 + mt*16 + lq]);
            *(uint4*)&WHP[(size_t)idx*8] = make_uint4(
                (unsigned int)v[0] | ((unsigned int)v[1] << 16),
                (unsigned int)v[2] | ((unsigned int)v[3] << 16),
                (unsigned int)v[4] | ((unsigned int)v[5] << 16),
                (unsigned int)v[6] | ((unsigned int)v[7] << 16));
        }
    }
}

// ============================================================================
// Kernel 1: MERGED encoders + queries (verified R13/R14/R16 body).
// ============================================================================
__global__ __launch_bounds__(256) void k_encq(
    const float* __restrict__ pred, const float* __restrict__ prey,
    const float* __restrict__ obst,
    const unsigned short* __restrict__ W2P, const float* __restrict__ BEP,
    const float* __restrict__ e0w1, const float* __restrict__ e0b1,
    const float* __restrict__ e1w1, const float* __restrict__ e1b1,
    const float* __restrict__ e2w1, const float* __restrict__ e2b1,
    const unsigned short* __restrict__ AqkP, const float* __restrict__ a0,
    const unsigned short* __restrict__ P3P,  const float* __restrict__ b0g0,
    unsigned short* __restrict__ X, float* __restrict__ POS,
    float* __restrict__ QT, float* __restrict__ QP, float* __restrict__ QC)
{
    const int tid = threadIdx.x, lane = tid & 63, w = tid >> 6;
    const int lq = lane & 15, quad = lane >> 4;
    __shared__ __align__(16) short sH[4][32][68];

    if (blockIdx.x < 1408) {
        const int blk = blockIdx.x;
        int type, lrow0, cin, lsh, nmask, nbase;
        const float *st, *w1, *b1;
        if (blk < 128)       { type=0; lrow0=blk*512;         st=pred; w1=e0w1; b1=e0b1; cin=2; lsh=7;  nmask=NPQ-1; nbase=0; }
        else if (blk < 1152) { type=1; lrow0=(blk-128)*512;   st=prey; w1=e1w1; b1=e1b1; cin=2; lsh=10; nmask=NY-1;  nbase=NPQ; }
        else                 { type=2; lrow0=(blk-1152)*512;  st=obst; w1=e2w1; b1=e2b1; cin=3; lsh=8;  nmask=NO-1;  nbase=NPQ+NY; }

        bf16x8 wfrag[4][2];
        #pragma unroll
        for (int mt = 0; mt < 4; ++mt)
            #pragma unroll
            for (int kh = 0; kh < 2; ++kh)
                wfrag[mt][kh] = *(const bf16x8*)&W2P[(size_t)(((type*4 + mt)*2 + kh)*64 + lane)*8];

        float4 be[4];
        #pragma unroll
        for (int mt = 0; mt < 4; ++mt)
            be[mt] = *(const float4*)&BEP[type*64 + mt*16 + quad*4];

        float b1v[2][8], w0v[2][8], w1v[2][8], w2v[2][8];
        #pragma unroll
        for (int kh = 0; kh < 2; ++kh) {
            const int k0 = kh*32 + quad*8;
            *(float4*)&b1v[kh][0] = *(const float4*)&b1[k0];
            *(float4*)&b1v[kh][4] = *(const float4*)&b1[k0+4];
            *(float4*)&w0v[kh][0] = *(const float4*)&w1[k0];
            *(float4*)&w0v[kh][4] = *(const float4*)&w1[k0+4];
            *(float4*)&w1v[kh][0] = *(const float4*)&w1[64+k0];
            *(float4*)&w1v[kh][4] = *(const float4*)&w1[64+k0+4];
            if (cin == 3) {
                *(float4*)&w2v[kh][0] = *(const float4*)&w1[128+k0];
                *(float4*)&w2v[kh][4] = *(const float4*)&w1[128+k0+4];
            }
        }

        #pragma unroll
        for (int k = 0; k < 4; ++k) {
            const int i = tid*4 + k;
            const int r = i >> 1, c = i & 1;
            const int lr = lrow0 + r;
            const int pb = lr >> lsh, n = nbase + (lr & nmask);
            POS[((size_t)pb*NTOT + n)*2 + c] = st[(size_t)lr*cin + c];
        }

        for (int rt = 0; rt < 8; ++rt) {
            const int lr = lrow0 + w*128 + rt*16 + lq;
            float s0, s1, s2 = 0.f;
            if (cin == 2) {
                const float2 sv = *(const float2*)&st[(size_t)lr*2];
                s0 = sv.x; s1 = sv.y;
            } else {
                const float2 sv = *(const float2*)&st[(size_t)lr*3];
                s0 = sv.x; s1 = sv.y; s2 = st[(size_t)lr*3 + 2];
            }
            bf16x8 hb[2];
            #pragma unroll
            for (int kh = 0; kh < 2; ++kh)
                #pragma unroll
                for (int j = 0; j < 8; ++j) {
                    float a = b1v[kh][j] + s0*w0v[kh][j] + s1*w1v[kh][j];
                    if (cin == 3) a += s2*w2v[kh][j];
                    hb[kh][j] = (short)f2bf(fmaxf(a, 0.f));
                }

            f32x4 acc[4];
            #pragma unroll
            for (int mt = 0; mt < 4; ++mt) acc[mt] = (f32x4){0.f,0.f,0.f,0.f};
            #pragma unroll
            for (int mt = 0; mt < 4; ++mt) {
                acc[mt] = __builtin_amdgcn_mfma_f32_16x16x32_bf16(wfrag[mt][0], hb[0], acc[mt], 0, 0, 0);
                acc[mt] = __builtin_amdgcn_mfma_f32_16x16x32_bf16(wfrag[mt][1], hb[1], acc[mt], 0, 0, 0);
            }

            const int bb = lr >> lsh, n = nbase + (lr & nmask);
            unsigned short* xbase = X + ((size_t)bb*NTOT + n)*64;
            #pragma unroll
            for (int mt = 0; mt < 4; ++mt) {
                const unsigned int u0 = (unsigned int)f2bf(acc[mt][0] + be[mt].x)
                                      | ((unsigned int)f2bf(acc[mt][1] + be[mt].y) << 16);
                const unsigned int u1 = (unsigned int)f2bf(acc[mt][2] + be[mt].z)
                                      | ((unsigned int)f2bf(acc[mt][3] + be[mt].w) << 16);
                *(uint2*)(xbase + mt*16 + quad*4) = make_uint2(u0, u1);
            }
        }
    } else {
        const int b = blockIdx.x - 1408;
        const float w1r0 = e0w1[lane], w1r1 = e0w1[64+lane], b1r = e0b1[lane];
        {
            const float* sp = pred + ((size_t)b*NPQ + w*32)*2;
            #pragma unroll
            for (int r = 0; r < 32; ++r) {
                const float a = b1r + sp[2*r]*w1r0 + sp[2*r+1]*w1r1;
                sH[w][r][lane] = (short)f2bf(fmaxf(a, 0.f));
            }
        }

        bf16x8 wfrag[4][2], a3[2];
        #pragma unroll
        for (int mt = 0; mt < 4; ++mt)
            #pragma unroll
            for (int kh = 0; kh < 2; ++kh)
                wfrag[mt][kh] = *(const bf16x8*)&AqkP[(size_t)((mt*2 + kh)*64 + lane)*8];
        #pragma unroll
        for (int kh = 0; kh < 2; ++kh)
            a3[kh] = *(const bf16x8*)&P3P[(size_t)(kh*64 + lane)*8];

        float4 a0r[4];
        #pragma unroll
        for (int mt = 0; mt < 4; ++mt) a0r[mt] = *(const float4*)&a0[mt*16 + quad*4];
        const float c0 = b0g0[0], c1 = b0g0[1], c2 = b0g0[2];

        __syncthreads();

        for (int bt = 0; bt < 2; ++bt) {
            U8 hb0, hb1;
            const short* hp = &sH[w][bt*16 + lq][0];
            hb0.u[0] = *(const unsigned long long*)(hp + quad*8);
            hb0.u[1] = *(const unsigned long long*)(hp + quad*8 + 4);
            hb1.u[0] = *(const unsigned long long*)(hp + 32 + quad*8);
            hb1.u[1] = *(const unsigned long long*)(hp + 32 + quad*8 + 4);

            f32x4 acc[4], acc3;
            #pragma unroll
            for (int mt = 0; mt < 4; ++mt) acc[mt] = (f32x4){0.f,0.f,0.f,0.f};
            acc3 = (f32x4){0.f,0.f,0.f,0.f};
            #pragma unroll
            for (int mt = 0; mt < 4; ++mt) {
                acc[mt] = __builtin_amdgcn_mfma_f32_16x16x32_bf16(wfrag[mt][0], hb0.v, acc[mt], 0, 0, 0);
                acc[mt] = __builtin_amdgcn_mfma_f32_16x16x32_bf16(wfrag[mt][1], hb1.v, acc[mt], 0, 0, 0);
            }
            acc3 = __builtin_amdgcn_mfma_f32_16x16x32_bf16(a3[0], hb0.v, acc3, 0, 0, 0);
            acc3 = __builtin_amdgcn_mfma_f32_16x16x32_bf16(a3[1], hb1.v, acc3, 0, 0, 0);

            const int row = b*NPQ + w*32 + bt*16 + lq;
            #pragma unroll
            for (int mt = 0; mt < 4; ++mt) {
                *(float4*)&QT[(size_t)row*64 + mt*16 + quad*4] = make_float4(
                    acc[mt][0] + a0r[mt].x, acc[mt][1] + a0r[mt].y,
                    acc[mt][2] + a0r[mt].z, acc[mt][3] + a0r[mt].w);
            }
            if (quad == 0) {
                const float qp0 = acc3[0] + c0, qp1 = acc3[1] + c1, qs = acc3[2] + c2;
                const float p0 = pred[(size_t)row*2], p1 = pred[(size_t)row*2 + 1];
                QP[(size_t)row*2]     = qp0;
                QP[(size_t)row*2 + 1] = qp1;
                QC[row] = qp0*p0 + qp1*p1 + qs;
            }
        }
    }
}

// ============================================================================
// Kernel 3: flash attention + fused head.
// R25 = R24 (80.4 µs, best) MINUS the sched_barrier(0).
//  Why now and not in R21: in R20/R22 the S-MFMAs consumed FRESHLY-ISSUED
//  global loads — lifting S above PV re-exposed vmcnt latency (R21: -12µs).
//  After R24's iteration-ahead prefetch, curA/curB/curP are registers whose
//  loads drained at the PREVIOUS __syncthreads (compiler emits full
//  s_waitcnt before s_barrier) — S has ZERO in-iteration memory dependence.
//  The barrier now only prevents the scheduler from weaving S's ~220-op
//  VALU tail (fmaf/exp2/f2bf) into PV's 16-MFMA shadow (MFMA and VALU are
//  separate pipes, co-issuable). The one true ordering constraint — sP
//  ds_read (PV) before sP ds_write (S) — is a same-address LDS dependence
//  the compiler preserves.
//  Canaries: WRITE_SIZE ~256 KB, bank conflicts 0. If this regresses >=85,
//  the barrier returns permanently and next lever is s_setprio (T5).
// ============================================================================
__device__ __forceinline__ void attn_iter(
    int kt, int b, int w, int lq, int quad, int skey, int sd0,
    const unsigned short* __restrict__ X, const float* __restrict__ POS,
    const bf16x8 (&aq)[2][2], const f32x4 (&qcv)[2],
    const float (&qp0r)[2][4], const float (&qp1r)[2][4],
    float (&lacc)[2][4], f32x4 (&O)[2][4],
    short (*sP)[32][68], short (*sXc)[64][68],
    U16 (&curA)[4], U16 (&curB)[4], float2 (&curP)[4],
    U16 (&nxtA)[4], U16 (&nxtB)[4], float2 (&nxtP)[4])
{
    const int par = kt & 1;

    // staging loads for tile kt (consumed at end of this iteration)
    const unsigned short* gx = X + ((size_t)b*NTOT + kt*64 + skey)*64 + sd0;
    const uint4 t0 = *(const uint4*)(gx);
    const uint4 t1 = *(const uint4*)(gx + 8);

    // R24: prefetch bx/POS for tile kt+1 (consumed by S in NEXT iteration)
    if (kt < 21) {
        #pragma unroll
        for (int nt = 0; nt < 4; ++nt) {
            const unsigned short* xrow = X + ((size_t)b*NTOT + (kt+1)*64 + nt*16 + lq)*64;
            nxtA[nt].u = *(const uint4*)(xrow + quad*8);
            nxtB[nt].u = *(const uint4*)(xrow + 32 + quad*8);
            nxtP[nt]   = *(const float2*)&POS[((size_t)b*NTOT + (kt+1)*64 + nt*16 + lq)*2];
        }
    }

    if (kt > 0) {
        const int pb = par ^ 1;
        #pragma unroll
        for (int kc = 0; kc < 2; ++kc) {
            U8 pa[2];
            #pragma unroll
            for (int qt = 0; qt < 2; ++qt) {
                const short* pp = &sP[w][qt*16 + lq][kc*32 + quad*8];
                pa[qt].u[0] = *(const unsigned long long*)pp;
                pa[qt].u[1] = *(const unsigned long long*)(pp + 4);
            }
            #pragma unroll
            for (int nt = 0; nt < 4; ++nt) {
                U8 bv;
                const short* xp = &sXc[pb][nt*16 + lq][kc*32 + quad*8];
                bv.u[0] = *(const unsigned long long*)xp;
                bv.u[1] = *(const unsigned long long*)(xp + 4);
                O[0][nt] = __builtin_amdgcn_mfma_f32_16x16x32_bf16(pa[0].v, bv.v, O[0][nt], 0, 0, 0);
                O[1][nt] = __builtin_amdgcn_mfma_f32_16x16x32_bf16(pa[1].v, bv.v, O[1][nt], 0, 0, 0);
            }
        }
    }

    // R25: sched_barrier(0) REMOVED — S's operands are iteration-old
    // registers, so the scheduler may now interleave S's VALU/trans tail
    // with PV's MFMAs (separate pipes).

    // S-block (R20 form) consuming the CURRENT (prefetched last iter) bx/POS.
    #pragma unroll
    for (int nt = 0; nt < 4; ++nt) {
        const float pos0 = curP[nt].x;
        const float pos1 = curP[nt].y;
        #pragma unroll
        for (int qt = 0; qt < 2; ++qt) {
            f32x4 sa = qcv[qt];   // R17: qcr as C-init (row const matches reg i)
            sa = __builtin_amdgcn_mfma_f32_16x16x32_bf16(aq[qt][0], curA[nt].v, sa, 0, 0, 0);
            sa = __builtin_amdgcn_mfma_f32_16x16x32_bf16(aq[qt][1], curB[nt].v, sa, 0, 0, 0);
            #pragma unroll
            for (int i = 0; i < 4; ++i) {
                float s = sa[i];
                s = fmaf(qp0r[qt][i], pos0, s);
                s = fmaf(qp1r[qt][i], pos1, s);
                const float p = exp2f(s);   // R17: E pre-folded upstream
                lacc[qt][i] += p;
                sP[w][qt*16 + quad*4 + i][nt*16 + lq] = (short)f2bf(p);
            }
        }
    }

    // staging writes for tile kt (transposed)
    {
        unsigned short tmp[16];
        *(uint4*)tmp = t0; *(uint4*)(tmp+8) = t1;
        #pragma unroll
        for (int j = 0; j < 16; ++j) sXc[par][sd0+j][skey] = (short)tmp[j];
    }

    __syncthreads();
}

__global__ __launch_bounds__(256) void k_attn(
    const unsigned short* __restrict__ X, const float* __restrict__ POS,
    const float* __restrict__ QT, const float* __restrict__ QP,
    const float* __restrict__ QC,
    const unsigned short* __restrict__ WHP,
    const float* __restrict__ bvo, const float* __restrict__ nb1,
    const float* __restrict__ nb2,
    const float* __restrict__ nw3, const float* __restrict__ nb3,
    float* __restrict__ OUT)
{
    const int tid = threadIdx.x, b = blockIdx.x;
    const int w = tid >> 6, lane = tid & 63, lq = lane & 15, quad = lane >> 4;

    // LDS union: [0,17408) = sXc | sA ; [17408,34816) = sP | sB ; then sw3.
    __shared__ __align__(16) char smem[34816 + 256];
    short (*sXc)[64][68] = (short (*)[64][68])(smem);          // [2][64][68]
    short (*sP )[32][68] = (short (*)[32][68])(smem + 17408);  // [4][32][68]
    short (*sA )[68]     = (short (*)[68])(smem);              // [128][68]
    short (*sB )[68]     = (short (*)[68])(smem + 17408);      // [128][68]
    float* sw3           = (float*)(smem + 34816);

    bf16x8 aq[2][2];
    #pragma unroll
    for (int qt = 0; qt < 2; ++qt) {
        const float* qrow = QT + ((size_t)b*NPQ + w*32 + qt*16 + lq)*64;
        #pragma unroll
        for (int kh = 0; kh < 2; ++kh)
            #pragma unroll
            for (int j = 0; j < 8; ++j)
                aq[qt][kh][j] = (short)f2bf(qrow[kh*32 + quad*8 + j]);
    }

    float qp0r[2][4], qp1r[2][4], lacc[2][4];
    f32x4 qcv[2];     // R17: C-initializer holding qcr per accumulator reg
    f32x4 O[2][4];
    #pragma unroll
    for (int qt = 0; qt < 2; ++qt)
        #pragma unroll
        for (int i = 0; i < 4; ++i) {
            const size_t g = (size_t)b*NPQ + w*32 + qt*16 + quad*4 + i;
            qcv[qt][i]  = QC[g];
            qp0r[qt][i] = -QP[2*g];
            qp1r[qt][i] = -QP[2*g+1];
            lacc[qt][i] = 0.f;
        }
    #pragma unroll
    for (int qt = 0; qt < 2; ++qt)
        #pragma unroll
        for (int nt = 0; nt < 4; ++nt) O[qt][nt] = (f32x4){0.f,0.f,0.f,0.f};

    const int skey = tid & 63, sd0 = (tid >> 6) * 16;

    // R24 prologue: prefetch bx/POS for tile 0 into buffer A.
    U16 bxaA[4], bxbA[4], bxaB[4], bxbB[4];
    float2 posvA[4], posvB[4];
    #pragma unroll
    for (int nt = 0; nt < 4; ++nt) {
        const unsigned short* xrow = X + ((size_t)b*NTOT + nt*16 + lq)*64;
        bxaA[nt].u = *(const uint4*)(xrow + quad*8);
        bxbA[nt].u = *(const uint4*)(xrow + 32 + quad*8);
        posvA[nt]  = *(const float2*)&POS[((size_t)b*NTOT + nt*16 + lq)*2];
    }

    // main loop, unrolled x2 for compile-time cur/nxt buffer selection
    for (int ktb = 0; ktb < 22; ktb += 2) {
        attn_iter(ktb,   b, w, lq, quad, skey, sd0, X, POS, aq, qcv, qp0r, qp1r,
                  lacc, O, sP, sXc, bxaA, bxbA, posvA, bxaB, bxbB, posvB);
        attn_iter(ktb+1, b, w, lq, quad, skey, sd0, X, POS, aq, qcv, qp0r, qp1r,
                  lacc, O, sP, sXc, bxaB, bxbB, posvB, bxaA, bxbA, posvA);
    }

    // ---- final PV: tile 21 (par=1) ----
    {
        #pragma unroll
        for (int kc = 0; kc < 2; ++kc) {
            U8 pa[2];
            #pragma unroll
            for (int qt = 0; qt < 2; ++qt) {
                const short* pp = &sP[w][qt*16 + lq][kc*32 + quad*8];
                pa[qt].u[0] = *(const unsigned long long*)pp;
                pa[qt].u[1] = *(const unsigned long long*)(pp + 4);
            }
            #pragma unroll
            for (int nt = 0; nt < 4; ++nt) {
                U8 bv;
                const short* xp = &sXc[1][nt*16 + lq][kc*32 + quad*8];
                bv.u[0] = *(const unsigned long long*)xp;
                bv.u[1] = *(const unsigned long long*)(xp + 4);
                O[0][nt] = __builtin_amdgcn_mfma_f32_16x16x32_bf16(pa[0].v, bv.v, O[0][nt], 0, 0, 0);
                O[1][nt] = __builtin_amdgcn_mfma_f32_16x16x32_bf16(pa[1].v, bv.v, O[1][nt], 0, 0, 0);
            }
        }
    }

    // R18: LDS union hazard fence — all waves must finish reading sXc[1]/sP
    // before the epilogue overwrites them through the sA alias.
    __syncthreads();

    // ---- attention epilogue -> sA (bf16) ----
    #pragma unroll
    for (int qt = 0; qt < 2; ++qt)
        #pragma unroll
        for (int i = 0; i < 4; ++i) {
            #pragma unroll
            for (int off = 1; off < 16; off <<= 1)
                lacc[qt][i] += __shfl_xor(lacc[qt][i], off);
            const float rl = 1.f / lacc[qt][i];
            const int row = w*32 + qt*16 + quad*4 + i;
            #pragma unroll
            for (int nt = 0; nt < 4; ++nt)
                sA[row][nt*16 + lq] = (short)f2bf(O[qt][nt][i] * rl);
        }
    if (tid < 64) sw3[tid] = nw3[tid];
    __syncthreads();   // sA complete before head reads (R2 lesson)

    // ---- fused head: 3 MFMA layers (verified k_head body) ----
    const float* Bs[3] = {bvo, nb1, nb2};
    for (int l = 0; l < 3; ++l) {
        bf16x8 wfrag[4][2];
        #pragma unroll
        for (int mt = 0; mt < 4; ++mt)
            #pragma unroll
            for (int kh = 0; kh < 2; ++kh)
                wfrag[mt][kh] = *(const bf16x8*)&WHP[(size_t)(((l*4 + mt)*2 + kh)*64 + lane)*8];
        const float* Bb = Bs[l];
        float be[4][4];
        #pragma unroll
        for (int mt = 0; mt < 4; ++mt)
            #pragma unroll
            for (int i = 0; i < 4; ++i) be[mt][i] = Bb[mt*16 + quad*4 + i];

        short (*src)[68] = (l & 1) ? sB : sA;
        short (*dst)[68] = (l & 1) ? sA : sB;
        const bool doRelu = (l >= 1);

        for (int bt = 0; bt < 2; ++bt) {
            U8 hb0, hb1;
            const short* hp = &src[w*32 + bt*16 + lq][0];
            hb0.u[0] = *(const unsigned long long*)(hp + quad*8);
            hb0.u[1] = *(const unsigned long long*)(hp + quad*8 + 4);
            hb1.u[0] = *(const unsigned long long*)(hp + 32 + quad*8);
            hb1.u[1] = *(const unsigned long long*)(hp + 32 + quad*8 + 4);

            f32x4 acc[4];
            #pragma unroll
            for (int mt = 0; mt < 4; ++mt) acc[mt] = (f32x4){0.f,0.f,0.f,0.f};
            #pragma unroll
            for (int mt = 0; mt < 4; ++mt) {
                acc[mt] = __builtin_amdgcn_mfma_f32_16x16x32_bf16(wfrag[mt][0], hb0.v, acc[mt], 0, 0, 0);
                acc[mt] = __builtin_amdgcn_mfma_f32_16x16x32_bf16(wfrag[mt][1], hb1.v, acc[mt], 0, 0, 0);
            }
            const int row = w*32 + bt*16 + lq;
            #pragma unroll
            for (int mt = 0; mt < 4; ++mt) {
                float v0 = acc[mt][0] + be[mt][0];
                float v1 = acc[mt][1] + be[mt][1];
                float v2 = acc[mt][2] + be[mt][2];
                float v3 = acc[mt][3] + be[mt][3];
                if (doRelu) {
                    v0 = fmaxf(v0, 0.f); v1 = fmaxf(v1, 0.f);
                    v2 = fmaxf(v2, 0.f); v3 = fmaxf(v3, 0.f);
                }
                const unsigned int u0 = (unsigned int)f2bf(v0) | ((unsigned int)f2bf(v1) << 16);
                const unsigned int u1 = (unsigned int)f2bf(v2) | ((unsigned int)f2bf(v3) << 16);
                *(uint2*)&dst[row][mt*16 + quad*4] = make_uint2(u0, u1);
            }
        }
        __syncthreads();
    }

    if (tid < 128) {
        const int row = tid;
        float acc = nb3[0];
        #pragma unroll 16
        for (int d = 0; d < 64; ++d) acc += bf2f(sB[row][d]) * sw3[d];
        OUT[(size_t)b*NPQ + row] = tanhf(acc);
    }
}

// ============================================================================
extern "C" void kernel_launch(void* const* d_in, const int* in_sizes, int n_in,
                              void* d_out, int out_size, void* d_ws, size_t ws_size,
                              hipStream_t stream)
{
    const float* pred = (const float*)d_in[0];
    const float* prey = (const float*)d_in[1];
    const float* obst = (const float*)d_in[2];
    const float* emb  = (const float*)d_in[4];
    const float* e0w1 = (const float*)d_in[5];
    const float* e0b1 = (const float*)d_in[6];
    const float* e0w2 = (const float*)d_in[7];
    const float* e0b2 = (const float*)d_in[8];
    const float* e1w1 = (const float*)d_in[9];
    const float* e1b1 = (const float*)d_in[10];
    const float* e1w2 = (const float*)d_in[11];
    const float* e1b2 = (const float*)d_in[12];
    const float* e2w1 = (const float*)d_in[13];
    const float* e2b1 = (const float*)d_in[14];
    const float* e2w2 = (const float*)d_in[15];
    const float* e2b2 = (const float*)d_in[16];
    const float* wq  = (const float*)d_in[17];
    const float* bq  = (const float*)d_in[18];
    const float* wk  = (const float*)d_in[19];
    const float* bk  = (const float*)d_in[20];
    const float* wvv = (const float*)d_in[21];
    const float* bv  = (const float*)d_in[22];
    const float* wp  = (const float*)d_in[23];
    const float* bp  = (const float*)d_in[24];
    const float* wo  = (const float*)d_in[25];
    const float* bo  = (const float*)d_in[26];
    const float* nw1 = (const float*)d_in[27];
    const float* nb1 = (const float*)d_in[28];
    const float* nw2 = (const float*)d_in[29];
    const float* nb2 = (const float*)d_in[30];
    const float* nw3 = (const float*)d_in[31];
    const float* nb3 = (const float*)d_in[32];

    char* ws = (char*)d_ws;
    unsigned short* X = (unsigned short*)ws;               // 92,274,688 B
    float* F    = (float*)(ws + 92274688);
    float* POS  = F;                  // 1,441,792
    float* QT   = POS + 1441792;      // 4,194,304
    float* QP   = QT  + 4194304;      // 131,072
    float* QC   = QP  + 131072;       // 65,536
    float* a0   = QC  + 65536;        // 64
    float* b0g0 = a0  + 64;           // 4
    float* bvo  = b0g0 + 4;           // 64
    float* BEP  = bvo + 64;           // 192
    float* W2qG = BEP + 192;          // 4,096
    float* WvoG = W2qG + 4096;        // 4,096
    float* scqG = WvoG + 4096;        // 64
    unsigned short* W2P  = (unsigned short*)(scqG + 64);   // 12,288
    unsigned short* AqkP = W2P + 12288;                    // 4,096
    unsigned short* P3P  = AqkP + 4096;                    // 1,024
    unsigned short* WHP  = P3P + 1024;                     // 12,288

    k_prepA<<<43, 256, 0, stream>>>(emb, e0b2, e0w2, wq, bq, wp, bp, bk,
        wvv, bv, wo, bo, e1b2, e1w2, e2b2, e2w2, nw1, nw2,
        W2qG, WvoG, scqG, b0g0, bvo, BEP, W2P, WHP);
    k_prepB<<<4, 256, 0, stream>>>(W2qG, WvoG, scqG, wk, wp, bp, bk,
        AqkP, P3P, a0, WHP);
    k_encq<<<1920, 256, 0, stream>>>(pred, prey, obst, W2P, BEP,
        e0w1, e0b1, e1w1, e1b1, e2w1, e2b1,
        AqkP, a0, P3P, b0g0, X, POS, QT, QP, QC);
    k_attn<<<512, 256, 0, stream>>>(X, POS, QT, QP, QC,
        WHP, bvo, nb1, nb2, nw3, nb3, (float*)d_out);
}

// Round 10
// 243.086 us; speedup vs baseline: 1.0939x; 1.0058x over previous
//
#include <hip/hip_runtime.h>
#include <math.h>

#define NB 512
#define NPQ 128
#define NY 1024
#define NO 256
#define NTOT 1408   // NPQ+NY+NO
#define SCALE_E 0.180336884f   // (1/sqrt(64)) * log2(e), folded upstream (R17)

typedef __attribute__((ext_vector_type(8))) short bf16x8;
typedef __attribute__((ext_vector_type(4))) float f32x4;

__device__ __forceinline__ unsigned short f2bf(float f) {
    unsigned int u = __float_as_uint(f);
    u += 0x7fffu + ((u >> 16) & 1u);   // RTNE
    return (unsigned short)(u >> 16);
}
__device__ __forceinline__ float bf2f(short s) {
    return __uint_as_float(((unsigned int)(unsigned short)s) << 16);
}

union U8  { bf16x8 v; unsigned long long u[2]; };
union U16 { bf16x8 v; uint4 u; };

// ============================================================================
// Kernel 0a: parallel weight folding, stage A. R17: b0g0 pre-scaled by E.
// ============================================================================
__global__ __launch_bounds__(256) void k_prepA(
    const float* __restrict__ emb,  const float* __restrict__ e0b2,
    const float* __restrict__ e0w2, const float* __restrict__ wq,
    const float* __restrict__ bq,   const float* __restrict__ wp,
    const float* __restrict__ bp,   const float* __restrict__ bk,
    const float* __restrict__ wvv,  const float* __restrict__ bv,
    const float* __restrict__ wo,   const float* __restrict__ bo,
    const float* __restrict__ e1b2, const float* __restrict__ e1w2,
    const float* __restrict__ e2b2, const float* __restrict__ e2w2,
    const float* __restrict__ nw1,  const float* __restrict__ nw2,
    float* __restrict__ W2qG, float* __restrict__ WvoG,
    float* __restrict__ scqG, float* __restrict__ b0g0,
    float* __restrict__ bvo,  float* __restrict__ BEP,
    unsigned short* __restrict__ W2P, unsigned short* __restrict__ WHP)
{
    const int tid = threadIdx.x, blk = blockIdx.x;

    if (blk < 16) {
        const int idx = blk*256 + tid;
        const int h = idx >> 6, j = idx & 63;
        float s0 = 0.f, s1 = 0.f, s2 = 0.f, s3 = 0.f;
        #pragma unroll 4
        for (int e = 0; e < 64; e += 4) {
            s0 = fmaf(e0w2[h*64+e],   wq[(e  )*64+j], s0);
            s1 = fmaf(e0w2[h*64+e+1], wq[(e+1)*64+j], s1);
            s2 = fmaf(e0w2[h*64+e+2], wq[(e+2)*64+j], s2);
            s3 = fmaf(e0w2[h*64+e+3], wq[(e+3)*64+j], s3);
        }
        W2qG[idx] = (s0 + s1) + (s2 + s3);
    } else if (blk < 32) {
        const int idx = (blk-16)*256 + tid;
        const int e = idx >> 6, o = idx & 63;
        float s0 = 0.f, s1 = 0.f, s2 = 0.f, s3 = 0.f;
        #pragma unroll 4
        for (int d = 0; d < 64; d += 4) {
            s0 = fmaf(wvv[e*64+d],   wo[(d  )*64+o], s0);
            s1 = fmaf(wvv[e*64+d+1], wo[(d+1)*64+o], s1);
            s2 = fmaf(wvv[e*64+d+2], wo[(d+2)*64+o], s2);
            s3 = fmaf(wvv[e*64+d+3], wo[(d+3)*64+o], s3);
        }
        WvoG[idx] = (s0 + s1) + (s2 + s3);
    } else if (blk < 38) {
        const int idx = (blk-32)*256 + tid;
        if (idx < 1536) {
            const int t = idx >> 9, rem = idx & 511;
            const int mt = rem >> 7, rem2 = rem & 127;
            const int kh = rem2 >> 6, lane = rem2 & 63;
            const int quad = lane >> 4, lq = lane & 15;
            const float* w2 = (t == 0) ? e0w2 : ((t == 1) ? e1w2 : e2w2);
            unsigned short v[8];
            #pragma unroll
            for (int j = 0; j < 8; ++j)
                v[j] = f2bf(w2[(kh*32 + quad*8 + j)*64 + mt*16 + lq]);
            *(uint4*)&W2P[(size_t)idx*8] = make_uint4(
                (unsigned int)v[0] | ((unsigned int)v[1] << 16),
                (unsigned int)v[2] | ((unsigned int)v[3] << 16),
                (unsigned int)v[4] | ((unsigned int)v[5] << 16),
                (unsigned int)v[6] | ((unsigned int)v[7] << 16));
        }
    } else if (blk < 42) {
        const int idx = 512 + (blk-38)*256 + tid;
        const int l = idx >> 9, rem = idx & 511;
        const int mt = rem >> 7, rem2 = rem & 127;
        const int kh = rem2 >> 6, lane = rem2 & 63;
        const int quad = lane >> 4, lq = lane & 15;
        const float* W = (l == 1) ? nw1 : nw2;
        unsigned short v[8];
        #pragma unroll
        for (int j = 0; j < 8; ++j)
            v[j] = f2bf(W[(kh*32 + quad*8 + j)*64 + mt*16 + lq]);
        *(uint4*)&WHP[(size_t)idx*8] = make_uint4(
            (unsigned int)v[0] | ((unsigned int)v[1] << 16),
            (unsigned int)v[2] | ((unsigned int)v[3] << 16),
            (unsigned int)v[4] | ((unsigned int)v[5] << 16),
            (unsigned int)v[6] | ((unsigned int)v[7] << 16));
    } else {
        __shared__ float scq[64];
        if (tid < 64) {
            const int j = tid;
            float s = bq[j];
            for (int e = 0; e < 64; ++e) s += (e0b2[e] + emb[e]) * wq[e*64+j];
            scq[j] = s;
            scqG[j] = s;
        }
        if (tid >= 64 && tid < 128) {
            const int o = tid - 64;
            float s = bo[o];
            for (int d = 0; d < 64; ++d) s += bv[d] * wo[d*64+o];
            bvo[o] = s;
        }
        {
            const int i = tid - 64;
            if (i >= 64 && i < 256) {
                const int idx = i - 64;   // 0..191
                const int t = idx >> 6, d = idx & 63;
                const float* b2 = (t == 0) ? e0b2 : ((t == 1) ? e1b2 : e2b2);
                BEP[idx] = b2[d] + emb[t*64 + d];
            }
        }
        __syncthreads();
        if (tid == 0) {
            float s0 = 0.f, s1 = 0.f, s2 = 0.f;
            for (int j = 0; j < 64; ++j) {
                s0 += scq[j] * wp[j];
                s1 += scq[j] * wp[64+j];
                s2 += scq[j] * (bp[j] + bk[j]);
            }
            b0g0[0] = SCALE_E * s0;    // R17: E folded upstream
            b0g0[1] = SCALE_E * s1;
            b0g0[2] = SCALE_E * s2;
        }
    }
}

// ============================================================================
// Kernel 0b: stage B. R17: AqkP / P3P / a0 pre-scaled by E.
// ============================================================================
__global__ __launch_bounds__(256) void k_prepB(
    const float* __restrict__ W2qG, const float* __restrict__ WvoG,
    const float* __restrict__ scqG,
    const float* __restrict__ wk, const float* __restrict__ wp,
    const float* __restrict__ bp, const float* __restrict__ bk,
    unsigned short* __restrict__ AqkP, unsigned short* __restrict__ P3P,
    float* __restrict__ a0, unsigned short* __restrict__ WHP)
{
    const int tid = threadIdx.x, blk = blockIdx.x;

    if (blk < 2) {
        const int idx = blk*256 + tid;
        const int fi = idx >> 6, lane = idx & 63;
        const int mt = fi >> 1, kh = fi & 1;
        const int quad = lane >> 4, lq = lane & 15;
        const int d = mt*16 + lq;
        unsigned short v[8];
        #pragma unroll
        for (int jj = 0; jj < 8; ++jj) {
            const int h = kh*32 + quad*8 + jj;
            float s0 = 0.f, s1 = 0.f, s2 = 0.f, s3 = 0.f;
            #pragma unroll 4
            for (int j = 0; j < 64; j += 4) {
                const float4 a = *(const float4*)&W2qG[h*64 + j];
                const float4 b = *(const float4*)&wk[d*64 + j];
                s0 = fmaf(a.x, b.x, s0); s1 = fmaf(a.y, b.y, s1);
                s2 = fmaf(a.z, b.z, s2); s3 = fmaf(a.w, b.w, s3);
            }
            v[jj] = f2bf(SCALE_E * ((s0 + s1) + (s2 + s3)));   // R17
        }
        *(uint4*)&AqkP[(size_t)idx*8] = make_uint4(
            (unsigned int)v[0] | ((unsigned int)v[1] << 16),
            (unsigned int)v[2] | ((unsigned int)v[3] << 16),
            (unsigned int)v[4] | ((unsigned int)v[5] << 16),
            (unsigned int)v[6] | ((unsigned int)v[7] << 16));
    } else if (blk == 2) {
        if (tid < 128) {
            const int idx = tid;
            const int kh = idx >> 6, lane = idx & 63;
            const int quad = lane >> 4, lq = lane & 15;
            unsigned short v[8];
            #pragma unroll
            for (int jj = 0; jj < 8; ++jj) {
                const int h = kh*32 + quad*8 + jj;
                float val = 0.f;
                if (lq == 0 || lq == 1) {
                    float s0 = 0.f, s1 = 0.f;
                    #pragma unroll 8
                    for (int j = 0; j < 64; j += 2) {
                        s0 = fmaf(W2qG[h*64+j],   wp[lq*64+j],   s0);
                        s1 = fmaf(W2qG[h*64+j+1], wp[lq*64+j+1], s1);
                    }
                    val = s0 + s1;
                } else if (lq == 2) {
                    float s0 = 0.f, s1 = 0.f;
                    #pragma unroll 8
                    for (int j = 0; j < 64; j += 2) {
                        s0 = fmaf(W2qG[h*64+j],   bp[j]   + bk[j],   s0);
                        s1 = fmaf(W2qG[h*64+j+1], bp[j+1] + bk[j+1], s1);
                    }
                    val = s0 + s1;
                }
                v[jj] = f2bf(SCALE_E * val);   // R17
            }
            *(uint4*)&P3P[(size_t)idx*8] = make_uint4(
                (unsigned int)v[0] | ((unsigned int)v[1] << 16),
                (unsigned int)v[2] | ((unsigned int)v[3] << 16),
                (unsigned int)v[4] | ((unsigned int)v[5] << 16),
                (unsigned int)v[6] | ((unsigned int)v[7] << 16));
        } else if (tid < 192) {
            const int d = tid - 128;
            float s0 = 0.f, s1 = 0.f, s2 = 0.f, s3 = 0.f;
            #pragma unroll 4
            for (int j = 0; j < 64; j += 4) {
                const float4 a = *(const float4*)&scqG[j];
                const float4 b = *(const float4*)&wk[d*64 + j];
                s0 = fmaf(a.x, b.x, s0); s1 = fmaf(a.y, b.y, s1);
                s2 = fmaf(a.z, b.z, s2); s3 = fmaf(a.w, b.w, s3);
            }
            a0[d] = SCALE_E * ((s0 + s1) + (s2 + s3));   // R17
        }
    } else {
        #pragma unroll
        for (int pass = 0; pass < 2; ++pass) {
            const int idx = pass*256 + tid;           // 0..511
            const int mt = idx >> 7, rem2 = idx & 127;
            const int kh = rem2 >> 6, lane = rem2 & 63;
            const int quad = lane >> 4, lq = lane & 15;
            unsigned short v[8];
            #pragma unroll
            for (int j = 0; j < 8; ++j)
                v[j] = f2bf(WvoG[(kh*32 + quad*8 + j)*64 + mt*16 + lq]);
            *(uint4*)&WHP[(size_t)idx*8] = make_uint4(
                (unsigned int)v[0] | ((unsigned int)v[1] << 16),
                (unsigned int)v[2] | ((unsigned int)v[3] << 16),
                (unsigned int)v[4] | ((unsigned int)v[5] << 16),
                (unsigned int)v[6] | ((unsigned int)v[7] << 16));
        }
    }
}

// ============================================================================
// Kernel 1: MERGED encoders + queries (verified R13/R14/R16 body).
// ============================================================================
__global__ __launch_bounds__(256) void k_encq(
    const float* __restrict__ pred, const float* __restrict__ prey,
    const float* __restrict__ obst,
    const unsigned short* __restrict__ W2P, const float* __restrict__ BEP,
    const float* __restrict__ e0w1, const float* __restrict__ e0b1,
    const float* __restrict__ e1w1, const float* __restrict__ e1b1,
    const float* __restrict__ e2w1, const float* __restrict__ e2b1,
    const unsigned short* __restrict__ AqkP, const float* __restrict__ a0,
    const unsigned short* __restrict__ P3P,  const float* __restrict__ b0g0,
    unsigned short* __restrict__ X, float* __restrict__ POS,
    float* __restrict__ QT, float* __restrict__ QP, float* __restrict__ QC)
{
    const int tid = threadIdx.x, lane = tid & 63, w = tid >> 6;
    const int lq = lane & 15, quad = lane >> 4;
    __shared__ __align__(16) short sH[4][32][68];

    if (blockIdx.x < 1408) {
        const int blk = blockIdx.x;
        int type, lrow0, cin, lsh, nmask, nbase;
        const float *st, *w1, *b1;
        if (blk < 128)       { type=0; lrow0=blk*512;         st=pred; w1=e0w1; b1=e0b1; cin=2; lsh=7;  nmask=NPQ-1; nbase=0; }
        else if (blk < 1152) { type=1; lrow0=(blk-128)*512;   st=prey; w1=e1w1; b1=e1b1; cin=2; lsh=10; nmask=NY-1;  nbase=NPQ; }
        else                 { type=2; lrow0=(blk-1152)*512;  st=obst; w1=e2w1; b1=e2b1; cin=3; lsh=8;  nmask=NO-1;  nbase=NPQ+NY; }

        bf16x8 wfrag[4][2];
        #pragma unroll
        for (int mt = 0; mt < 4; ++mt)
            #pragma unroll
            for (int kh = 0; kh < 2; ++kh)
                wfrag[mt][kh] = *(const bf16x8*)&W2P[(size_t)(((type*4 + mt)*2 + kh)*64 + lane)*8];

        float4 be[4];
        #pragma unroll
        for (int mt = 0; mt < 4; ++mt)
            be[mt] = *(const float4*)&BEP[type*64 + mt*16 + quad*4];

        float b1v[2][8], w0v[2][8], w1v[2][8], w2v[2][8];
        #pragma unroll
        for (int kh = 0; kh < 2; ++kh) {
            const int k0 = kh*32 + quad*8;
            *(float4*)&b1v[kh][0] = *(const float4*)&b1[k0];
            *(float4*)&b1v[kh][4] = *(const float4*)&b1[k0+4];
            *(float4*)&w0v[kh][0] = *(const float4*)&w1[k0];
            *(float4*)&w0v[kh][4] = *(const float4*)&w1[k0+4];
            *(float4*)&w1v[kh][0] = *(const float4*)&w1[64+k0];
            *(float4*)&w1v[kh][4] = *(const float4*)&w1[64+k0+4];
            if (cin == 3) {
                *(float4*)&w2v[kh][0] = *(const float4*)&w1[128+k0];
                *(float4*)&w2v[kh][4] = *(const float4*)&w1[128+k0+4];
            }
        }

        #pragma unroll
        for (int k = 0; k < 4; ++k) {
            const int i = tid*4 + k;
            const int r = i >> 1, c = i & 1;
            const int lr = lrow0 + r;
            const int pb = lr >> lsh, n = nbase + (lr & nmask);
            POS[((size_t)pb*NTOT + n)*2 + c] = st[(size_t)lr*cin + c];
        }

        for (int rt = 0; rt < 8; ++rt) {
            const int lr = lrow0 + w*128 + rt*16 + lq;
            float s0, s1, s2 = 0.f;
            if (cin == 2) {
                const float2 sv = *(const float2*)&st[(size_t)lr*2];
                s0 = sv.x; s1 = sv.y;
            } else {
                const float2 sv = *(const float2*)&st[(size_t)lr*3];
                s0 = sv.x; s1 = sv.y; s2 = st[(size_t)lr*3 + 2];
            }
            bf16x8 hb[2];
            #pragma unroll
            for (int kh = 0; kh < 2; ++kh)
                #pragma unroll
                for (int j = 0; j < 8; ++j) {
                    float a = b1v[kh][j] + s0*w0v[kh][j] + s1*w1v[kh][j];
                    if (cin == 3) a += s2*w2v[kh][j];
                    hb[kh][j] = (short)f2bf(fmaxf(a, 0.f));
                }

            f32x4 acc[4];
            #pragma unroll
            for (int mt = 0; mt < 4; ++mt) acc[mt] = (f32x4){0.f,0.f,0.f,0.f};
            #pragma unroll
            for (int mt = 0; mt < 4; ++mt) {
                acc[mt] = __builtin_amdgcn_mfma_f32_16x16x32_bf16(wfrag[mt][0], hb[0], acc[mt], 0, 0, 0);
                acc[mt] = __builtin_amdgcn_mfma_f32_16x16x32_bf16(wfrag[mt][1], hb[1], acc[mt], 0, 0, 0);
            }

            const int bb = lr >> lsh, n = nbase + (lr & nmask);
            unsigned short* xbase = X + ((size_t)bb*NTOT + n)*64;
            #pragma unroll
            for (int mt = 0; mt < 4; ++mt) {
                const unsigned int u0 = (unsigned int)f2bf(acc[mt][0] + be[mt].x)
                                      | ((unsigned int)f2bf(acc[mt][1] + be[mt].y) << 16);
                const unsigned int u1 = (unsigned int)f2bf(acc[mt][2] + be[mt].z)
                                      | ((unsigned int)f2bf(acc[mt][3] + be[mt].w) << 16);
                *(uint2*)(xbase + mt*16 + quad*4) = make_uint2(u0, u1);
            }
        }
    } else {
        const int b = blockIdx.x - 1408;
        const float w1r0 = e0w1[lane], w1r1 = e0w1[64+lane], b1r = e0b1[lane];
        {
            const float* sp = pred + ((size_t)b*NPQ + w*32)*2;
            #pragma unroll
            for (int r = 0; r < 32; ++r) {
                const float a = b1r + sp[2*r]*w1r0 + sp[2*r+1]*w1r1;
                sH[w][r][lane] = (short)f2bf(fmaxf(a, 0.f));
            }
        }

        bf16x8 wfrag[4][2], a3[2];
        #pragma unroll
        for (int mt = 0; mt < 4; ++mt)
            #pragma unroll
            for (int kh = 0; kh < 2; ++kh)
                wfrag[mt][kh] = *(const bf16x8*)&AqkP[(size_t)((mt*2 + kh)*64 + lane)*8];
        #pragma unroll
        for (int kh = 0; kh < 2; ++kh)
            a3[kh] = *(const bf16x8*)&P3P[(size_t)(kh*64 + lane)*8];

        float4 a0r[4];
        #pragma unroll
        for (int mt = 0; mt < 4; ++mt) a0r[mt] = *(const float4*)&a0[mt*16 + quad*4];
        const float c0 = b0g0[0], c1 = b0g0[1], c2 = b0g0[2];

        __syncthreads();

        for (int bt = 0; bt < 2; ++bt) {
            U8 hb0, hb1;
            const short* hp = &sH[w][bt*16 + lq][0];
            hb0.u[0] = *(const unsigned long long*)(hp + quad*8);
            hb0.u[1] = *(const unsigned long long*)(hp + quad*8 + 4);
            hb1.u[0] = *(const unsigned long long*)(hp + 32 + quad*8);
            hb1.u[1] = *(const unsigned long long*)(hp + 32 + quad*8 + 4);

            f32x4 acc[4], acc3;
            #pragma unroll
            for (int mt = 0; mt < 4; ++mt) acc[mt] = (f32x4){0.f,0.f,0.f,0.f};
            acc3 = (f32x4){0.f,0.f,0.f,0.f};
            #pragma unroll
            for (int mt = 0; mt < 4; ++mt) {
                acc[mt] = __builtin_amdgcn_mfma_f32_16x16x32_bf16(wfrag[mt][0], hb0.v, acc[mt], 0, 0, 0);
                acc[mt] = __builtin_amdgcn_mfma_f32_16x16x32_bf16(wfrag[mt][1], hb1.v, acc[mt], 0, 0, 0);
            }
            acc3 = __builtin_amdgcn_mfma_f32_16x16x32_bf16(a3[0], hb0.v, acc3, 0, 0, 0);
            acc3 = __builtin_amdgcn_mfma_f32_16x16x32_bf16(a3[1], hb1.v, acc3, 0, 0, 0);

            const int row = b*NPQ + w*32 + bt*16 + lq;
            #pragma unroll
            for (int mt = 0; mt < 4; ++mt) {
                *(float4*)&QT[(size_t)row*64 + mt*16 + quad*4] = make_float4(
                    acc[mt][0] + a0r[mt].x, acc[mt][1] + a0r[mt].y,
                    acc[mt][2] + a0r[mt].z, acc[mt][3] + a0r[mt].w);
            }
            if (quad == 0) {
                const float qp0 = acc3[0] + c0, qp1 = acc3[1] + c1, qs = acc3[2] + c2;
                const float p0 = pred[(size_t)row*2], p1 = pred[(size_t)row*2 + 1];
                QP[(size_t)row*2]     = qp0;
                QP[(size_t)row*2 + 1] = qp1;
                QC[row] = qp0*p0 + qp1*p1 + qs;
            }
        }
    }
}

// ============================================================================
// Kernel 3: flash attention + fused head.
// R26 = R25 (78.7 µs, best) + s_setprio(1) around the PV MFMA clusters (T5).
//  Mechanism: 2 independent blocks/CU whose waves sit at DIFFERENT phases
//  (one block's waves in S's VALU tail while the other's enter PV). setprio
//  biases CU arbitration toward the MFMA-issuing wave, keeping the matrix
//  pipe fed (measured +4-7% on attention-shaped kernels, m191; helps only
//  with phase diversity — our blocks are independent, unlike the R19 case).
//  Everything else byte-level R25.
//  Canaries: WRITE_SIZE ~256 KB, bank conflicts 0, VGPR ~128.
// ============================================================================
__device__ __forceinline__ void attn_iter(
    int kt, int b, int w, int lq, int quad, int skey, int sd0,
    const unsigned short* __restrict__ X, const float* __restrict__ POS,
    const bf16x8 (&aq)[2][2], const f32x4 (&qcv)[2],
    const float (&qp0r)[2][4], const float (&qp1r)[2][4],
    float (&lacc)[2][4], f32x4 (&O)[2][4],
    short (*sP)[32][68], short (*sXc)[64][68],
    U16 (&curA)[4], U16 (&curB)[4], float2 (&curP)[4],
    U16 (&nxtA)[4], U16 (&nxtB)[4], float2 (&nxtP)[4])
{
    const int par = kt & 1;

    // staging loads for tile kt (consumed at end of this iteration)
    const unsigned short* gx = X + ((size_t)b*NTOT + kt*64 + skey)*64 + sd0;
    const uint4 t0 = *(const uint4*)(gx);
    const uint4 t1 = *(const uint4*)(gx + 8);

    // R24: prefetch bx/POS for tile kt+1 (consumed by S in NEXT iteration)
    if (kt < 21) {
        #pragma unroll
        for (int nt = 0; nt < 4; ++nt) {
            const unsigned short* xrow = X + ((size_t)b*NTOT + (kt+1)*64 + nt*16 + lq)*64;
            nxtA[nt].u = *(const uint4*)(xrow + quad*8);
            nxtB[nt].u = *(const uint4*)(xrow + 32 + quad*8);
            nxtP[nt]   = *(const float2*)&POS[((size_t)b*NTOT + (kt+1)*64 + nt*16 + lq)*2];
        }
    }

    if (kt > 0) {
        const int pb = par ^ 1;
        __builtin_amdgcn_s_setprio(1);   // R26: favor PV's MFMA cluster
        #pragma unroll
        for (int kc = 0; kc < 2; ++kc) {
            U8 pa[2];
            #pragma unroll
            for (int qt = 0; qt < 2; ++qt) {
                const short* pp = &sP[w][qt*16 + lq][kc*32 + quad*8];
                pa[qt].u[0] = *(const unsigned long long*)pp;
                pa[qt].u[1] = *(const unsigned long long*)(pp + 4);
            }
            #pragma unroll
            for (int nt = 0; nt < 4; ++nt) {
                U8 bv;
                const short* xp = &sXc[pb][nt*16 + lq][kc*32 + quad*8];
                bv.u[0] = *(const unsigned long long*)xp;
                bv.u[1] = *(const unsigned long long*)(xp + 4);
                O[0][nt] = __builtin_amdgcn_mfma_f32_16x16x32_bf16(pa[0].v, bv.v, O[0][nt], 0, 0, 0);
                O[1][nt] = __builtin_amdgcn_mfma_f32_16x16x32_bf16(pa[1].v, bv.v, O[1][nt], 0, 0, 0);
            }
        }
        __builtin_amdgcn_s_setprio(0);   // R26
    }

    // R25: no sched_barrier — S's operands are iteration-old registers.

    // S-block (R20 form) consuming the CURRENT (prefetched last iter) bx/POS.
    #pragma unroll
    for (int nt = 0; nt < 4; ++nt) {
        const float pos0 = curP[nt].x;
        const float pos1 = curP[nt].y;
        #pragma unroll
        for (int qt = 0; qt < 2; ++qt) {
            f32x4 sa = qcv[qt];   // R17: qcr as C-init (row const matches reg i)
            sa = __builtin_amdgcn_mfma_f32_16x16x32_bf16(aq[qt][0], curA[nt].v, sa, 0, 0, 0);
            sa = __builtin_amdgcn_mfma_f32_16x16x32_bf16(aq[qt][1], curB[nt].v, sa, 0, 0, 0);
            #pragma unroll
            for (int i = 0; i < 4; ++i) {
                float s = sa[i];
                s = fmaf(qp0r[qt][i], pos0, s);
                s = fmaf(qp1r[qt][i], pos1, s);
                const float p = exp2f(s);   // R17: E pre-folded upstream
                lacc[qt][i] += p;
                sP[w][qt*16 + quad*4 + i][nt*16 + lq] = (short)f2bf(p);
            }
        }
    }

    // staging writes for tile kt (transposed)
    {
        unsigned short tmp[16];
        *(uint4*)tmp = t0; *(uint4*)(tmp+8) = t1;
        #pragma unroll
        for (int j = 0; j < 16; ++j) sXc[par][sd0+j][skey] = (short)tmp[j];
    }

    __syncthreads();
}

__global__ __launch_bounds__(256) void k_attn(
    const unsigned short* __restrict__ X, const float* __restrict__ POS,
    const float* __restrict__ QT, const float* __restrict__ QP,
    const float* __restrict__ QC,
    const unsigned short* __restrict__ WHP,
    const float* __restrict__ bvo, const float* __restrict__ nb1,
    const float* __restrict__ nb2,
    const float* __restrict__ nw3, const float* __restrict__ nb3,
    float* __restrict__ OUT)
{
    const int tid = threadIdx.x, b = blockIdx.x;
    const int w = tid >> 6, lane = tid & 63, lq = lane & 15, quad = lane >> 4;

    // LDS union: [0,17408) = sXc | sA ; [17408,34816) = sP | sB ; then sw3.
    __shared__ __align__(16) char smem[34816 + 256];
    short (*sXc)[64][68] = (short (*)[64][68])(smem);          // [2][64][68]
    short (*sP )[32][68] = (short (*)[32][68])(smem + 17408);  // [4][32][68]
    short (*sA )[68]     = (short (*)[68])(smem);              // [128][68]
    short (*sB )[68]     = (short (*)[68])(smem + 17408);      // [128][68]
    float* sw3           = (float*)(smem + 34816);

    bf16x8 aq[2][2];
    #pragma unroll
    for (int qt = 0; qt < 2; ++qt) {
        const float* qrow = QT + ((size_t)b*NPQ + w*32 + qt*16 + lq)*64;
        #pragma unroll
        for (int kh = 0; kh < 2; ++kh)
            #pragma unroll
            for (int j = 0; j < 8; ++j)
                aq[qt][kh][j] = (short)f2bf(qrow[kh*32 + quad*8 + j]);
    }

    float qp0r[2][4], qp1r[2][4], lacc[2][4];
    f32x4 qcv[2];     // R17: C-initializer holding qcr per accumulator reg
    f32x4 O[2][4];
    #pragma unroll
    for (int qt = 0; qt < 2; ++qt)
        #pragma unroll
        for (int i = 0; i < 4; ++i) {
            const size_t g = (size_t)b*NPQ + w*32 + qt*16 + quad*4 + i;
            qcv[qt][i]  = QC[g];
            qp0r[qt][i] = -QP[2*g];
            qp1r[qt][i] = -QP[2*g+1];
            lacc[qt][i] = 0.f;
        }
    #pragma unroll
    for (int qt = 0; qt < 2; ++qt)
        #pragma unroll
        for (int nt = 0; nt < 4; ++nt) O[qt][nt] = (f32x4){0.f,0.f,0.f,0.f};

    const int skey = tid & 63, sd0 = (tid >> 6) * 16;

    // R24 prologue: prefetch bx/POS for tile 0 into buffer A.
    U16 bxaA[4], bxbA[4], bxaB[4], bxbB[4];
    float2 posvA[4], posvB[4];
    #pragma unroll
    for (int nt = 0; nt < 4; ++nt) {
        const unsigned short* xrow = X + ((size_t)b*NTOT + nt*16 + lq)*64;
        bxaA[nt].u = *(const uint4*)(xrow + quad*8);
        bxbA[nt].u = *(const uint4*)(xrow + 32 + quad*8);
        posvA[nt]  = *(const float2*)&POS[((size_t)b*NTOT + nt*16 + lq)*2];
    }

    // main loop, unrolled x2 for compile-time cur/nxt buffer selection
    for (int ktb = 0; ktb < 22; ktb += 2) {
        attn_iter(ktb,   b, w, lq, quad, skey, sd0, X, POS, aq, qcv, qp0r, qp1r,
                  lacc, O, sP, sXc, bxaA, bxbA, posvA, bxaB, bxbB, posvB);
        attn_iter(ktb+1, b, w, lq, quad, skey, sd0, X, POS, aq, qcv, qp0r, qp1r,
                  lacc, O, sP, sXc, bxaB, bxbB, posvB, bxaA, bxbA, posvA);
    }

    // ---- final PV: tile 21 (par=1) ----
    {
        __builtin_amdgcn_s_setprio(1);   // R26
        #pragma unroll
        for (int kc = 0; kc < 2; ++kc) {
            U8 pa[2];
            #pragma unroll
            for (int qt = 0; qt < 2; ++qt) {
                const short* pp = &sP[w][qt*16 + lq][kc*32 + quad*8];
                pa[qt].u[0] = *(const unsigned long long*)pp;
                pa[qt].u[1] = *(const unsigned long long*)(pp + 4);
            }
            #pragma unroll
            for (int nt = 0; nt < 4; ++nt) {
                U8 bv;
                const short* xp = &sXc[1][nt*16 + lq][kc*32 + quad*8];
                bv.u[0] = *(const unsigned long long*)xp;
                bv.u[1] = *(const unsigned long long*)(xp + 4);
                O[0][nt] = __builtin_amdgcn_mfma_f32_16x16x32_bf16(pa[0].v, bv.v, O[0][nt], 0, 0, 0);
                O[1][nt] = __builtin_amdgcn_mfma_f32_16x16x32_bf16(pa[1].v, bv.v, O[1][nt], 0, 0, 0);
            }
        }
        __builtin_amdgcn_s_setprio(0);   // R26
    }

    // R18: LDS union hazard fence — all waves must finish reading sXc[1]/sP
    // before the epilogue overwrites them through the sA alias.
    __syncthreads();

    // ---- attention epilogue -> sA (bf16) ----
    #pragma unroll
    for (int qt = 0; qt < 2; ++qt)
        #pragma unroll
        for (int i = 0; i < 4; ++i) {
            #pragma unroll
            for (int off = 1; off < 16; off <<= 1)
                lacc[qt][i] += __shfl_xor(lacc[qt][i], off);
            const float rl = 1.f / lacc[qt][i];
            const int row = w*32 + qt*16 + quad*4 + i;
            #pragma unroll
            for (int nt = 0; nt < 4; ++nt)
                sA[row][nt*16 + lq] = (short)f2bf(O[qt][nt][i] * rl);
        }
    if (tid < 64) sw3[tid] = nw3[tid];
    __syncthreads();   // sA complete before head reads (R2 lesson)

    // ---- fused head: 3 MFMA layers (verified k_head body) ----
    const float* Bs[3] = {bvo, nb1, nb2};
    for (int l = 0; l < 3; ++l) {
        bf16x8 wfrag[4][2];
        #pragma unroll
        for (int mt = 0; mt < 4; ++mt)
            #pragma unroll
            for (int kh = 0; kh < 2; ++kh)
                wfrag[mt][kh] = *(const bf16x8*)&WHP[(size_t)(((l*4 + mt)*2 + kh)*64 + lane)*8];
        const float* Bb = Bs[l];
        float be[4][4];
        #pragma unroll
        for (int mt = 0; mt < 4; ++mt)
            #pragma unroll
            for (int i = 0; i < 4; ++i) be[mt][i] = Bb[mt*16 + quad*4 + i];

        short (*src)[68] = (l & 1) ? sB : sA;
        short (*dst)[68] = (l & 1) ? sA : sB;
        const bool doRelu = (l >= 1);

        for (int bt = 0; bt < 2; ++bt) {
            U8 hb0, hb1;
            const short* hp = &src[w*32 + bt*16 + lq][0];
            hb0.u[0] = *(const unsigned long long*)(hp + quad*8);
            hb0.u[1] = *(const unsigned long long*)(hp + quad*8 + 4);
            hb1.u[0] = *(const unsigned long long*)(hp + 32 + quad*8);
            hb1.u[1] = *(const unsigned long long*)(hp + 32 + quad*8 + 4);

            f32x4 acc[4];
            #pragma unroll
            for (int mt = 0; mt < 4; ++mt) acc[mt] = (f32x4){0.f,0.f,0.f,0.f};
            #pragma unroll
            for (int mt = 0; mt < 4; ++mt) {
                acc[mt] = __builtin_amdgcn_mfma_f32_16x16x32_bf16(wfrag[mt][0], hb0.v, acc[mt], 0, 0, 0);
                acc[mt] = __builtin_amdgcn_mfma_f32_16x16x32_bf16(wfrag[mt][1], hb1.v, acc[mt], 0, 0, 0);
            }
            const int row = w*32 + bt*16 + lq;
            #pragma unroll
            for (int mt = 0; mt < 4; ++mt) {
                float v0 = acc[mt][0] + be[mt][0];
                float v1 = acc[mt][1] + be[mt][1];
                float v2 = acc[mt][2] + be[mt][2];
                float v3 = acc[mt][3] + be[mt][3];
                if (doRelu) {
                    v0 = fmaxf(v0, 0.f); v1 = fmaxf(v1, 0.f);
                    v2 = fmaxf(v2, 0.f); v3 = fmaxf(v3, 0.f);
                }
                const unsigned int u0 = (unsigned int)f2bf(v0) | ((unsigned int)f2bf(v1) << 16);
                const unsigned int u1 = (unsigned int)f2bf(v2) | ((unsigned int)f2bf(v3) << 16);
                *(uint2*)&dst[row][mt*16 + quad*4] = make_uint2(u0, u1);
            }
        }
        __syncthreads();
    }

    if (tid < 128) {
        const int row = tid;
        float acc = nb3[0];
        #pragma unroll 16
        for (int d = 0; d < 64; ++d) acc += bf2f(sB[row][d]) * sw3[d];
        OUT[(size_t)b*NPQ + row] = tanhf(acc);
    }
}

// ============================================================================
extern "C" void kernel_launch(void* const* d_in, const int* in_sizes, int n_in,
                              void* d_out, int out_size, void* d_ws, size_t ws_size,
                              hipStream_t stream)
{
    const float* pred = (const float*)d_in[0];
    const float* prey = (const float*)d_in[1];
    const float* obst = (const float*)d_in[2];
    const float* emb  = (const float*)d_in[4];
    const float* e0w1 = (const float*)d_in[5];
    const float* e0b1 = (const float*)d_in[6];
    const float* e0w2 = (const float*)d_in[7];
    const float* e0b2 = (const float*)d_in[8];
    const float* e1w1 = (const float*)d_in[9];
    const float* e1b1 = (const float*)d_in[10];
    const float* e1w2 = (const float*)d_in[11];
    const float* e1b2 = (const float*)d_in[12];
    const float* e2w1 = (const float*)d_in[13];
    const float* e2b1 = (const float*)d_in[14];
    const float* e2w2 = (const float*)d_in[15];
    const float* e2b2 = (const float*)d_in[16];
    const float* wq  = (const float*)d_in[17];
    const float* bq  = (const float*)d_in[18];
    const float* wk  = (const float*)d_in[19];
    const float* bk  = (const float*)d_in[20];
    const float* wvv = (const float*)d_in[21];
    const float* bv  = (const float*)d_in[22];
    const float* wp  = (const float*)d_in[23];
    const float* bp  = (const float*)d_in[24];
    const float* wo  = (const float*)d_in[25];
    const float* bo  = (const float*)d_in[26];
    const float* nw1 = (const float*)d_in[27];
    const float* nb1 = (const float*)d_in[28];
    const float* nw2 = (const float*)d_in[29];
    const float* nb2 = (const float*)d_in[30];
    const float* nw3 = (const float*)d_in[31];
    const float* nb3 = (const float*)d_in[32];

    char* ws = (char*)d_ws;
    unsigned short* X = (unsigned short*)ws;               // 92,274,688 B
    float* F    = (float*)(ws + 92274688);
    float* POS  = F;                  // 1,441,792
    float* QT   = POS + 1441792;      // 4,194,304
    float* QP   = QT  + 4194304;      // 131,072
    float* QC   = QP  + 131072;       // 65,536
    float* a0   = QC  + 65536;        // 64
    float* b0g0 = a0  + 64;           // 4
    float* bvo  = b0g0 + 4;           // 64
    float* BEP  = bvo + 64;           // 192
    float* W2qG = BEP + 192;          // 4,096
    float* WvoG = W2qG + 4096;        // 4,096
    float* scqG = WvoG + 4096;        // 64
    unsigned short* W2P  = (unsigned short*)(scqG + 64);   // 12,288
    unsigned short* AqkP = W2P + 12288;                    // 4,096
    unsigned short* P3P  = AqkP + 4096;                    // 1,024
    unsigned short* WHP  = P3P + 1024;                     // 12,288

    k_prepA<<<43, 256, 0, stream>>>(emb, e0b2, e0w2, wq, bq, wp, bp, bk,
        wvv, bv, wo, bo, e1b2, e1w2, e2b2, e2w2, nw1, nw2,
        W2qG, WvoG, scqG, b0g0, bvo, BEP, W2P, WHP);
    k_prepB<<<4, 256, 0, stream>>>(W2qG, WvoG, scqG, wk, wp, bp, bk,
        AqkP, P3P, a0, WHP);
    k_encq<<<1920, 256, 0, stream>>>(pred, prey, obst, W2P, BEP,
        e0w1, e0b1, e1w1, e1b1, e2w1, e2b1,
        AqkP, a0, P3P, b0g0, X, POS, QT, QP, QC);
    k_attn<<<512, 256, 0, stream>>>(X, POS, QT, QP, QC,
        WHP, bvo, nb1, nb2, nw3, nb3, (float*)d_out);
}